// Round 18
// baseline (319.639 us; speedup 1.0000x reference)
//
#include <hip/hip_runtime.h>
#include <hip/hip_bf16.h>

typedef __attribute__((ext_vector_type(8))) __bf16 bf16x8;
typedef __attribute__((ext_vector_type(8))) unsigned short us8;
typedef __attribute__((ext_vector_type(4))) float f32x4;
typedef long long ll;

#define GLD(gp, lp) __builtin_amdgcn_global_load_lds( \
    (const __attribute__((address_space(1))) void*)(gp), \
    (__attribute__((address_space(3))) void*)(lp), 16, 0, 0)

#define SBAR()  asm volatile("s_barrier" ::: "memory")
#define VMCNT4  asm volatile("s_waitcnt vmcnt(4)" ::: "memory")
#define VMCNT0  asm volatile("s_waitcnt vmcnt(0)" ::: "memory")

// ---------------------------------------------------------------------------
// 256x256-tile 8-phase GEMM (round-9 structure; r18: sched_barrier(0) fences
// REMOVED — m201 template has none; barriers alone carry the cross-wave LDS
// ordering, MFMA is register-only so compiler reordering is dep-safe).
// OP 0: proj C=bf16 (+bias)
// OP 1: scores C=bf16 exp(v/32, masked; skip tiles); fused col-sums -> part;
//        diagonal blocks: waves with fully-masked quadrants skip MFMA.
// OP 2: PV (fallback path only)
// ---------------------------------------------------------------------------
template<int OP>
__global__ __launch_bounds__(512) void gemm8(
    const __bf16* __restrict__ A, const __bf16* __restrict__ B,
    void* __restrict__ Cp, const float* __restrict__ bias,
    const int* __restrict__ maskp, float* __restrict__ part,
    int K, int lda, int ldb, int ldc,
    ll batchA, ll batchB, ll batchC)
{
    __shared__ __bf16 LA[2][256][64];
    __shared__ __bf16 LB[2][256][64];

    const int bx = blockIdx.x, by = blockIdx.y, bz = blockIdx.z;
    const int t    = threadIdx.x;
    const int w    = t >> 6, lane = t & 63;
    const int wrm  = w >> 2, wcn  = w & 3;
    const int fr   = lane & 15, fq = lane >> 4;
    const int row0 = bx * 256;
    const int col0 = by * 256;
    const int msk  = (OP >= 1) ? maskp[0] : 0;

    if (OP == 1 && msk && by > bx) {
        __bf16* C = (__bf16*)Cp + (ll)bz * batchC;
        bf16x8 z = {};
        #pragma unroll 4
        for (int pass = 0; pass < 16; ++pass) {
            int r = pass * 16 + (t >> 5);
            *(bf16x8*)&C[(ll)(row0 + r) * ldc + col0 + (t & 31) * 8] = z;
        }
        if (part && t < 256) part[((ll)bx * 8 + bz) * 2048 + col0 + t] = 0.f;
        return;
    }

    // wave-level skip: diagonal tiles, quadrant entirely above diagonal
    const bool wskip = (OP == 1) && msk && (by == bx) && (wcn * 64 > wrm * 128 + 127);

    int NT = K / 64;
    if (OP == 2 && msk) NT = (row0 + 256) / 64;
    const int NI = NT / 2;

    const __bf16* Ab = A + (ll)bz * batchA;
    const __bf16* Bb = B + (ll)bz * batchB;

    const int srow = lane >> 3;
    const int cg   = (lane & 7) ^ srow;

    auto stageA = [&](int kt, int h, int slot) {
        #pragma unroll
        for (int is = 0; is < 2; ++is)
            GLD(Ab + (ll)(row0 + h*128 + is*64 + w*8 + srow) * lda + kt*64 + cg*8,
                &LA[slot][h*128 + is*64 + w*8][0]);
    };
    auto stageB = [&](int kt, int h, int slot) {
        #pragma unroll
        for (int is = 0; is < 2; ++is)
            GLD(Bb + (ll)(col0 + h*128 + is*64 + w*8 + srow) * ldb + kt*64 + cg*8,
                &LB[slot][h*128 + is*64 + w*8][0]);
    };
    auto rdA = [&](int slot, int row, int g) -> bf16x8 {
        return *(const bf16x8*)&LA[slot][row][(g ^ (row & 7)) << 3];
    };
    auto rdB = [&](int slot, int row, int g) -> bf16x8 {
        return *(const bf16x8*)&LB[slot][row][(g ^ (row & 7)) << 3];
    };

    f32x4  acc[8][4] = {};
    bf16x8 bB[4][2];

    stageA(0, 0, 0); stageA(0, 1, 0);
    stageB(0, 0, 0); stageB(0, 1, 0);
    stageB(1, 0, 1); stageB(1, 1, 1);
    VMCNT4;
    SBAR();

#define PHASE(SLOT, Q, STG, VMC) \
  { \
    if (Q == 0) { \
      _Pragma("unroll") for (int j = 0; j < 4; ++j) \
      _Pragma("unroll") for (int ks = 0; ks < 2; ++ks) \
        bB[j][ks] = rdB(SLOT, wcn*64 + j*16 + fr, ks*4 + fq); \
    } \
    bf16x8 bA[2][2]; \
    _Pragma("unroll") for (int fi = 0; fi < 2; ++fi) \
    _Pragma("unroll") for (int ks = 0; ks < 2; ++ks) \
      bA[fi][ks] = rdA(SLOT, wrm*128 + (Q*2+fi)*16 + fr, ks*4 + fq); \
    STG; \
    VMC; \
    SBAR(); \
    if (!wskip) { \
      __builtin_amdgcn_s_setprio(1); \
      _Pragma("unroll") for (int fi = 0; fi < 2; ++fi) \
      _Pragma("unroll") for (int j = 0; j < 4; ++j) \
      _Pragma("unroll") for (int ks = 0; ks < 2; ++ks) \
        acc[Q*2+fi][j] = __builtin_amdgcn_mfma_f32_16x16x32_bf16( \
            bA[fi][ks], bB[j][ks], acc[Q*2+fi][j], 0, 0, 0); \
      __builtin_amdgcn_s_setprio(0); \
    } \
    SBAR(); \
  }

    for (int i = 0; i < NI; ++i) {
        const bool nl = (i < NI - 1);
        const int k1 = 2*i + 1, k2 = 2*i + 2, k3 = 2*i + 3;
        PHASE(0, 0, stageA(k1, 0, 1), );
        PHASE(0, 1, stageA(k1, 1, 1), );
        PHASE(0, 2, if (nl) stageB(k2, 0, 0), );
        PHASE(0, 3, if (nl) stageB(k2, 1, 0), if (nl) { VMCNT4; } else { VMCNT0; });
        PHASE(1, 0, if (nl) stageA(k2, 0, 0), );
        PHASE(1, 1, if (nl) stageA(k2, 1, 0), );
        PHASE(1, 2, if (nl) stageB(k3, 0, 1), );
        PHASE(1, 3, if (nl) stageB(k3, 1, 1), if (nl) { VMCNT4; });
    }
#undef PHASE

    const ll coff = (ll)bz * batchC;
    float s4[4] = {0.f, 0.f, 0.f, 0.f};
    #pragma unroll
    for (int fi = 0; fi < 8; ++fi)
    #pragma unroll
    for (int j = 0; j < 4; ++j)
    #pragma unroll
    for (int r4 = 0; r4 < 4; ++r4) {
        const int row = row0 + wrm*128 + fi*16 + fq*4 + r4;
        const int col = col0 + wcn*64 + j*16 + fr;
        float v = acc[fi][j][r4];
        if (OP == 0) {
            v += bias[col];
            ((__bf16*)Cp)[coff + (ll)row * ldc + col] = (__bf16)v;
        } else if (OP == 1) {
            float e = (msk && col > row) ? 0.f : __expf(v * 0.03125f);
            __bf16 eb = (__bf16)e;
            ((__bf16*)Cp)[coff + (ll)row * ldc + col] = eb;
            s4[j] += (float)eb;
        } else {
            ((float*)Cp)[coff + (ll)row * ldc + col] = v;
        }
    }
    if (OP == 1 && part != nullptr) {
        float* red = (float*)&LA[0][0][0];
        __syncthreads();
        #pragma unroll
        for (int j = 0; j < 4; ++j)
            red[(wrm*4 + fq)*256 + wcn*64 + j*16 + fr] = s4[j];
        __syncthreads();
        if (t < 256) {
            float tot = 0.f;
            #pragma unroll
            for (int r = 0; r < 8; ++r) tot += red[r*256 + t];
            part[((ll)bx * 8 + bz) * 2048 + col0 + t] = tot;
        }
    }
}

// ---------------------------------------------------------------------------
// PV (round-17 structure; r18: sched_barrier fences removed, same audit).
// BM=64/BN=256, 2 blocks/CU, interleaved attn slices w/ masked fast path.
// ---------------------------------------------------------------------------
__global__ __launch_bounds__(512) void pv64(
    const __bf16* __restrict__ E, const __bf16* __restrict__ VT,
    const float* __restrict__ inv, float* __restrict__ out,
    float* __restrict__ attn, const int* __restrict__ maskp)
{
    __shared__ __bf16 LA[2][64][64];     // 16 KB
    __shared__ __bf16 LB[2][256][64];    // 64 KB

    const int n   = blockIdx.x;
    const int by  = n & 3;
    const int bxr = 31 - (n >> 2);       // longest first
    const int bz  = blockIdx.z;
    const int t = threadIdx.x, w = t >> 6, lane = t & 63;
    const int wrm = w >> 2, wcn = w & 3;
    const int fr = lane & 15, fq = lane >> 4;
    const int row0 = bxr * 64, col0 = by * 256;
    const int msk = maskp[0];

    int NT = msk ? ((bxr + 2) & ~1) : 32;
    const int NI = NT / 2;

    const __bf16* Ab = E  + (ll)bz * 2048 * 2048;
    const __bf16* Bb = VT + (ll)bz * 1024 * 2048;

    // attn-slice setup: cols by*512..+512, rows row0..+64 (8 slices x 8 rows)
    const int c0 = by * 512;
    const int ct = (t & 63) * 8;
    const int r00 = t >> 6;              // 0..7
    f32x4 ivlo = *(const f32x4*)&inv[bz*2048 + c0 + ct];
    f32x4 ivhi = *(const f32x4*)&inv[bz*2048 + c0 + ct + 4];

    auto slice = [&](int s) {
        const int row = row0 + s*8 + r00;
        float* ao = attn + (ll)bz*2048*2048 + (ll)row*2048 + c0 + ct;
        if (msk && c0 > row0 + s*8 + 7) {      // whole slice above diagonal
            f32x4 z = {};
            ((f32x4*)ao)[0] = z;
            ((f32x4*)ao)[1] = z;
            return;
        }
        bf16x8 ev = *(const bf16x8*)&Ab[(ll)row*2048 + c0 + ct];
        f32x4 lo, hi;
        #pragma unroll
        for (int e = 0; e < 4; ++e) {
            lo[e] = (float)ev[e]     * ivlo[e];
            hi[e] = (float)ev[e + 4] * ivhi[e];
        }
        ((f32x4*)ao)[0] = lo;
        ((f32x4*)ao)[1] = hi;
    };

    const int srow = lane >> 3;
    const int cg   = (lane & 7) ^ srow;

    auto stageA = [&](int kt, int slot) {
        GLD(Ab + (ll)(row0 + w*8 + srow) * 2048 + kt*64 + cg*8,
            &LA[slot][w*8][0]);
    };
    auto stageB = [&](int kt, int slot) {
        #pragma unroll
        for (int h = 0; h < 2; ++h)
        #pragma unroll
        for (int is = 0; is < 2; ++is)
            GLD(Bb + (ll)(col0 + h*128 + is*64 + w*8 + srow) * 2048 + kt*64 + cg*8,
                &LB[slot][h*128 + is*64 + w*8][0]);
    };
    auto rdA = [&](int slot, int row, int g) -> bf16x8 {
        return *(const bf16x8*)&LA[slot][row][(g ^ (row & 7)) << 3];
    };
    auto rdB = [&](int slot, int row, int g) -> bf16x8 {
        return *(const bf16x8*)&LB[slot][row][(g ^ (row & 7)) << 3];
    };

    f32x4  acc[2][4] = {};
    bf16x8 bB[4][2];

    // prologue
    stageA(0, 0); stageB(0, 0);
    stageB(1, 1);
    VMCNT4;
    SBAR();

#define PHASEP(SLOT, Q, STG, VMC) \
  { \
    if (Q == 0) { \
      _Pragma("unroll") for (int j = 0; j < 4; ++j) \
      _Pragma("unroll") for (int ks = 0; ks < 2; ++ks) \
        bB[j][ks] = rdB(SLOT, wcn*64 + j*16 + fr, ks*4 + fq); \
    } \
    bf16x8 bA[2]; \
    _Pragma("unroll") for (int ks = 0; ks < 2; ++ks) \
      bA[ks] = rdA(SLOT, wrm*32 + Q*16 + fr, ks*4 + fq); \
    STG; \
    VMC; \
    SBAR(); \
    __builtin_amdgcn_s_setprio(1); \
    _Pragma("unroll") for (int j = 0; j < 4; ++j) \
    _Pragma("unroll") for (int ks = 0; ks < 2; ++ks) \
      acc[Q][j] = __builtin_amdgcn_mfma_f32_16x16x32_bf16( \
          bA[ks], bB[j][ks], acc[Q][j], 0, 0, 0); \
    __builtin_amdgcn_s_setprio(0); \
    SBAR(); \
  }

    for (int i = 0; i < NI; ++i) {
        const bool nl = (i < NI - 1);
        const int kb = 2*i + 1, ka2 = 2*i + 2, kb2 = 2*i + 3;
        PHASEP(0, 0, stageA(kb, 1), );
        PHASEP(0, 1, if (nl) stageB(ka2, 0),
                     if (nl) { VMCNT4; } else { VMCNT0; });
        PHASEP(1, 0, if (nl) stageA(ka2, 0), );
        PHASEP(1, 1, if (nl) stageB(kb2, 1),
                     if (nl) { VMCNT4; });
        if (i < 8) slice(i);             // overlapped attn write
    }
#undef PHASEP

    // remaining attn slices (short-K blocks)
    for (int s = (NI < 8 ? NI : 8); s < 8; ++s) slice(s);

    // out stores
    #pragma unroll
    for (int qf = 0; qf < 2; ++qf)
    #pragma unroll
    for (int j = 0; j < 4; ++j)
    #pragma unroll
    for (int r4 = 0; r4 < 4; ++r4) {
        const int row = row0 + wrm*32 + qf*16 + fq*4 + r4;
        const int col = col0 + wcn*64 + j*16 + fr;
        out[(ll)bz*2048*1024 + (ll)row*1024 + col] = acc[qf][j][r4];
    }
}

// ---------------------------------------------------------------------------
// All input conversions in ONE launch.
// Blocks [0,8192): X -> Xb ; [8192,8704): Wq ; [8704,9216): Wk ;
// [9216,9728): Wv ; [9728,9740): bias concat. Grid 9740 x 256.
// ---------------------------------------------------------------------------
__global__ __launch_bounds__(256) void cvtall_k(
    const float* __restrict__ X,  const float* __restrict__ Wq,
    const float* __restrict__ Wk, const float* __restrict__ Wv,
    const float* __restrict__ bq, const float* __restrict__ bk,
    const float* __restrict__ bv,
    __bf16* __restrict__ Xb, __bf16* __restrict__ Wb, float* __restrict__ bb)
{
    const int b = blockIdx.x;
    if (b < 9728) {
        const float* src;
        __bf16* dst;
        ll i;
        if (b < 8192)      { src = X;  dst = Xb;             i = (ll)b * 256 + threadIdx.x; }
        else if (b < 8704) { src = Wq; dst = Wb;             i = (ll)(b - 8192) * 256 + threadIdx.x; }
        else if (b < 9216) { src = Wk; dst = Wb + 1024*1024; i = (ll)(b - 8704) * 256 + threadIdx.x; }
        else               { src = Wv; dst = Wb + 2048*1024; i = (ll)(b - 9216) * 256 + threadIdx.x; }
        const f32x4* p = (const f32x4*)(src + i * 8);
        f32x4 a = p[0], c = p[1];
        bf16x8 h;
        #pragma unroll
        for (int j = 0; j < 4; ++j) { h[j] = (__bf16)a[j]; h[j + 4] = (__bf16)c[j]; }
        *(bf16x8*)(dst + i * 8) = h;
    } else {
        const int i = (b - 9728) * 256 + threadIdx.x;   // 0..3071
        bb[i] = (i < 1024) ? bq[i] : (i < 2048) ? bk[i - 1024] : bv[i - 2048];
    }
}

// ---------------------------------------------------------------------------
__global__ __launch_bounds__(256) void rsum_k(const float* __restrict__ part,
                                              float* __restrict__ inv)
{
    const int idx = blockIdx.x * 256 + threadIdx.x;
    const int b = idx >> 11, m = idx & 2047;
    float s = 0.f;
    #pragma unroll
    for (int lc = 0; lc < 8; ++lc) s += part[((ll)lc * 8 + b) * 2048 + m];
    inv[idx] = 1.0f / s;
}

// ---------------------------------------------------------------------------
__global__ __launch_bounds__(256) void vtp_k(const __bf16* __restrict__ qkv,
                                             const float* __restrict__ inv,
                                             __bf16* __restrict__ vt)
{
    __shared__ __bf16 tile[64][72];
    const int t  = threadIdx.x;
    const int m0 = blockIdx.x * 64;
    const int k0 = blockIdx.y * 64;
    const int b  = blockIdx.z;

    const __bf16* V = qkv + (ll)b * 2048 * 3072 + 2048;
    #pragma unroll
    for (int h = 0; h < 2; ++h) {
        int r = (t >> 3) + h * 32;
        int c = (t & 7) * 8;
        int m = m0 + r;
        const float iv = inv[b * 2048 + m];
        bf16x8 v = *(const bf16x8*)&V[(ll)m * 3072 + k0 + c];
        bf16x8 o;
        #pragma unroll
        for (int j = 0; j < 8; ++j) o[j] = (__bf16)((float)v[j] * iv);
        *(bf16x8*)&tile[r][c] = o;
    }
    __syncthreads();
    __bf16* O = vt + (ll)b * 1024 * 2048;
    #pragma unroll
    for (int h = 0; h < 2; ++h) {
        int k = (t >> 3) + h * 32;
        int m = (t & 7) * 8;
        bf16x8 o;
        #pragma unroll
        for (int j = 0; j < 8; ++j) o[j] = tile[m + j][k];
        *(bf16x8*)&O[(ll)(k0 + k) * 2048 + m0 + m] = o;
    }
}

// plain V transpose (fallback path)
__global__ __launch_bounds__(256) void vt_k(const unsigned short* __restrict__ qkv,
                                            unsigned short* __restrict__ vt)
{
    __shared__ unsigned short tile[64][72];
    const int t  = threadIdx.x;
    const int m0 = blockIdx.x * 64;
    const int k0 = blockIdx.y * 64;
    const int b  = blockIdx.z;

    const unsigned short* V = qkv + (ll)b * 2048 * 3072 + 2048;
    #pragma unroll
    for (int h = 0; h < 2; ++h) {
        int r = (t >> 3) + h * 32;
        int c = (t & 7) * 8;
        us8 v = *(const us8*)&V[(ll)(m0 + r) * 3072 + k0 + c];
        *(us8*)&tile[r][c] = v;
    }
    __syncthreads();
    unsigned short* O = vt + (ll)b * 1024 * 2048;
    #pragma unroll
    for (int h = 0; h < 2; ++h) {
        int k = (t >> 3) + h * 32;
        int m = (t & 7) * 8;
        us8 o;
        #pragma unroll
        for (int j = 0; j < 8; ++j) o[j] = tile[m + j][k];
        *(us8*)&O[(ll)(k0 + k) * 2048 + m0 + m] = o;
    }
}

// fallback-path aux
__global__ __launch_bounds__(256) void colsum_k(const __bf16* __restrict__ E,
                                                float* __restrict__ part)
{
    const int lc = blockIdx.x, mc = blockIdx.y, b = blockIdx.z;
    const int m  = mc * 256 + threadIdx.x;
    const __bf16* p = E + (ll)b * 2048 * 2048 + (ll)(lc * 256) * 2048 + m;
    float s = 0.f;
    #pragma unroll 4
    for (int l = 0; l < 256; ++l) s += (float)p[(ll)l * 2048];
    part[((ll)lc * 8 + b) * 2048 + m] = s;
}

__global__ __launch_bounds__(256) void norm_k(const __bf16* __restrict__ E,
                                              const float* __restrict__ part,
                                              float* __restrict__ attn,
                                              __bf16* __restrict__ attn_bf)
{
    const int lc = blockIdx.x, mc = blockIdx.y, b = blockIdx.z;
    const int m  = mc * 256 + threadIdx.x;
    float s = 0.f;
    #pragma unroll
    for (int j = 0; j < 8; ++j) s += part[((ll)j * 8 + b) * 2048 + m];
    const float iv = 1.0f / s;
    const __bf16* p = E + (ll)b * 2048 * 2048 + (ll)(lc * 256) * 2048 + m;
    float*  qo = attn    + (ll)b * 2048 * 2048 + (ll)(lc * 256) * 2048 + m;
    __bf16* ro = attn_bf + (ll)b * 2048 * 2048 + (ll)(lc * 256) * 2048 + m;
    #pragma unroll 4
    for (int l = 0; l < 256; ++l) {
        float a = (float)p[(ll)l * 2048] * iv;
        qo[(ll)l * 2048] = a;
        ro[(ll)l * 2048] = (__bf16)a;
    }
}

// ---------------------------------------------------------------------------
extern "C" void kernel_launch(void* const* d_in, const int* in_sizes, int n_in,
                              void* d_out, int out_size, void* d_ws, size_t ws_size,
                              hipStream_t stream)
{
    const float* X   = (const float*)d_in[0];
    const float* Wq  = (const float*)d_in[1];
    const float* bq  = (const float*)d_in[2];
    const float* Wk  = (const float*)d_in[3];
    const float* bk  = (const float*)d_in[4];
    const float* Wv  = (const float*)d_in[5];
    const float* bv  = (const float*)d_in[6];
    const int*   msk = (const int*)d_in[7];

    float* out  = (float*)d_out;                  // (8,2048,1024) fp32
    float* attn = out + (ll)8 * 2048 * 1024;      // (8,2048,2048) fp32

    __bf16* Xb = (__bf16*)attn;                   // staging in attn region
    __bf16* Wb = Xb + (ll)16384 * 1024;
    float*  bb = (float*)(Wb + (ll)3072 * 1024);

    __bf16* qkv = (__bf16*)d_ws;                  // 96 MiB
    __bf16* vt  = qkv + (ll)16384 * 3072;         // 32 MiB

    // 0) all bf16 conversions in one launch
    cvtall_k<<<dim3(9740), 256, 0, stream>>>(X, Wq, Wk, Wv, bq, bk, bv,
                                             Xb, Wb, bb);

    // 1) QKV projection
    gemm8<0><<<dim3(64, 12, 1), 512, 0, stream>>>(
        Xb, Wb, qkv, bb, msk, nullptr,
        1024, 1024, 1024, 3072, 0LL, 0LL, 0LL);

    const size_t need_fused =
        (size_t)(16384ll*3072 + 8ll*1024*2048 + 8ll*2048*2048) * 2
        + (size_t)(8*8*2048 + 8*2048) * 4;

    if (ws_size >= need_fused) {
        // fused path: E in ws, inv folded into V^T, attn fused into PV
        __bf16* E   = vt + (ll)8 * 1024 * 2048;
        float*  prt = (float*)(E + (ll)8 * 2048 * 2048);
        float*  inv = prt + 8 * 8 * 2048;

        // 2) E = exp(QK^T/32, masked) -> ws; fused column partial sums
        gemm8<1><<<dim3(8, 8, 8), 512, 0, stream>>>(
            qkv, qkv + 1024, E, nullptr, msk, prt,
            1024, 3072, 3072, 2048,
            (ll)2048 * 3072, (ll)2048 * 3072, (ll)2048 * 2048);

        // 3) inv = 1/colsum
        rsum_k<<<dim3(64), 256, 0, stream>>>(prt, inv);

        // 4) vt = (V * inv)^T
        vtp_k<<<dim3(32, 16, 8), 256, 0, stream>>>(qkv, inv, vt);

        // 5) out = E @ vt^T  +  attn = E*inv interleaved (masked fast path)
        pv64<<<dim3(128, 1, 8), 512, 0, stream>>>(E, vt, inv, out, attn, msk);
    } else {
        // fallback: round-4 proven pipeline
        __bf16* E   = (__bf16*)d_out;
        float*  prt = (float*)(vt + (ll)8 * 1024 * 2048);
        __bf16* attn_bf = qkv;

        vt_k<<<dim3(32, 16, 8), 256, 0, stream>>>((const unsigned short*)qkv,
                                                  (unsigned short*)vt);

        gemm8<1><<<dim3(8, 8, 8), 512, 0, stream>>>(
            qkv, qkv + 1024, E, nullptr, msk, nullptr,
            1024, 3072, 3072, 2048,
            (ll)2048 * 3072, (ll)2048 * 3072, (ll)2048 * 2048);

        colsum_k<<<dim3(8, 8, 8), 256, 0, stream>>>(E, prt);
        norm_k<<<dim3(8, 8, 8), 256, 0, stream>>>(E, prt, attn, attn_bf);

        gemm8<2><<<dim3(8, 4, 8), 512, 0, stream>>>(
            attn_bf, vt, out, nullptr, msk, nullptr,
            2048, 2048, 2048, 1024,
            (ll)2048 * 2048, (ll)1024 * 2048, (ll)2048 * 1024);
    }
}

// Round 19
// 311.560 us; speedup vs baseline: 1.0259x; 1.0259x over previous
//
#include <hip/hip_runtime.h>
#include <hip/hip_bf16.h>

typedef __attribute__((ext_vector_type(8))) __bf16 bf16x8;
typedef __attribute__((ext_vector_type(8))) unsigned short us8;
typedef __attribute__((ext_vector_type(4))) float f32x4;
typedef long long ll;

#define GLD(gp, lp) __builtin_amdgcn_global_load_lds( \
    (const __attribute__((address_space(1))) void*)(gp), \
    (__attribute__((address_space(3))) void*)(lp), 16, 0, 0)

#define SBAR()  asm volatile("s_barrier" ::: "memory")
#define VMCNT4  asm volatile("s_waitcnt vmcnt(4)" ::: "memory")
#define VMCNT0  asm volatile("s_waitcnt vmcnt(0)" ::: "memory")
#define SCHED0() __builtin_amdgcn_sched_barrier(0)

// ---------------------------------------------------------------------------
// 256x256-tile 8-phase GEMM (round-17 config — best measured, frozen).
// OP 0: proj C=bf16 (+bias)
// OP 1: scores C=bf16 exp(v/32, masked; skip tiles; r19: tiles with
//        by-bx>=3 are never read downstream -> skip E zero-fill entirely.
//        Audit: PV reads E cols < row+128 (by<=bx+1); attn slices read
//        cols < c0+512 with c0<=row (by<=bx+2). part still zeroed.)
//        Fused col-sums -> part; diagonal-tile wave skip.
// OP 2: PV (fallback path only)
// ---------------------------------------------------------------------------
template<int OP>
__global__ __launch_bounds__(512) void gemm8(
    const __bf16* __restrict__ A, const __bf16* __restrict__ B,
    void* __restrict__ Cp, const float* __restrict__ bias,
    const int* __restrict__ maskp, float* __restrict__ part,
    int K, int lda, int ldb, int ldc,
    ll batchA, ll batchB, ll batchC)
{
    __shared__ __bf16 LA[2][256][64];
    __shared__ __bf16 LB[2][256][64];

    const int bx = blockIdx.x, by = blockIdx.y, bz = blockIdx.z;
    const int t    = threadIdx.x;
    const int w    = t >> 6, lane = t & 63;
    const int wrm  = w >> 2, wcn  = w & 3;
    const int fr   = lane & 15, fq = lane >> 4;
    const int row0 = bx * 256;
    const int col0 = by * 256;
    const int msk  = (OP >= 1) ? maskp[0] : 0;

    if (OP == 1 && msk && by > bx) {
        if (part && t < 256) part[((ll)bx * 8 + bz) * 2048 + col0 + t] = 0.f;
        if (by - bx >= 3) return;              // dead tile: never read
        __bf16* C = (__bf16*)Cp + (ll)bz * batchC;
        bf16x8 z = {};
        #pragma unroll 4
        for (int pass = 0; pass < 16; ++pass) {
            int r = pass * 16 + (t >> 5);
            *(bf16x8*)&C[(ll)(row0 + r) * ldc + col0 + (t & 31) * 8] = z;
        }
        return;
    }

    // wave-level skip: diagonal tiles, quadrant entirely above diagonal
    const bool wskip = (OP == 1) && msk && (by == bx) && (wcn * 64 > wrm * 128 + 127);

    int NT = K / 64;
    if (OP == 2 && msk) NT = (row0 + 256) / 64;
    const int NI = NT / 2;

    const __bf16* Ab = A + (ll)bz * batchA;
    const __bf16* Bb = B + (ll)bz * batchB;

    const int srow = lane >> 3;
    const int cg   = (lane & 7) ^ srow;

    auto stageA = [&](int kt, int h, int slot) {
        #pragma unroll
        for (int is = 0; is < 2; ++is)
            GLD(Ab + (ll)(row0 + h*128 + is*64 + w*8 + srow) * lda + kt*64 + cg*8,
                &LA[slot][h*128 + is*64 + w*8][0]);
    };
    auto stageB = [&](int kt, int h, int slot) {
        #pragma unroll
        for (int is = 0; is < 2; ++is)
            GLD(Bb + (ll)(col0 + h*128 + is*64 + w*8 + srow) * ldb + kt*64 + cg*8,
                &LB[slot][h*128 + is*64 + w*8][0]);
    };
    auto rdA = [&](int slot, int row, int g) -> bf16x8 {
        return *(const bf16x8*)&LA[slot][row][(g ^ (row & 7)) << 3];
    };
    auto rdB = [&](int slot, int row, int g) -> bf16x8 {
        return *(const bf16x8*)&LB[slot][row][(g ^ (row & 7)) << 3];
    };

    f32x4  acc[8][4] = {};
    bf16x8 bB[4][2];

    stageA(0, 0, 0); stageA(0, 1, 0);
    stageB(0, 0, 0); stageB(0, 1, 0);
    stageB(1, 0, 1); stageB(1, 1, 1);
    VMCNT4;
    SBAR();

#define PHASE(SLOT, Q, STG, VMC) \
  { \
    if (Q == 0) { \
      _Pragma("unroll") for (int j = 0; j < 4; ++j) \
      _Pragma("unroll") for (int ks = 0; ks < 2; ++ks) \
        bB[j][ks] = rdB(SLOT, wcn*64 + j*16 + fr, ks*4 + fq); \
    } \
    bf16x8 bA[2][2]; \
    _Pragma("unroll") for (int fi = 0; fi < 2; ++fi) \
    _Pragma("unroll") for (int ks = 0; ks < 2; ++ks) \
      bA[fi][ks] = rdA(SLOT, wrm*128 + (Q*2+fi)*16 + fr, ks*4 + fq); \
    STG; \
    VMC; \
    SBAR(); SCHED0(); \
    if (!wskip) { \
      __builtin_amdgcn_s_setprio(1); \
      _Pragma("unroll") for (int fi = 0; fi < 2; ++fi) \
      _Pragma("unroll") for (int j = 0; j < 4; ++j) \
      _Pragma("unroll") for (int ks = 0; ks < 2; ++ks) \
        acc[Q*2+fi][j] = __builtin_amdgcn_mfma_f32_16x16x32_bf16( \
            bA[fi][ks], bB[j][ks], acc[Q*2+fi][j], 0, 0, 0); \
      __builtin_amdgcn_s_setprio(0); \
    } \
    SCHED0(); SBAR(); \
  }

    for (int i = 0; i < NI; ++i) {
        const bool nl = (i < NI - 1);
        const int k1 = 2*i + 1, k2 = 2*i + 2, k3 = 2*i + 3;
        PHASE(0, 0, stageA(k1, 0, 1), );
        PHASE(0, 1, stageA(k1, 1, 1), );
        PHASE(0, 2, if (nl) stageB(k2, 0, 0), );
        PHASE(0, 3, if (nl) stageB(k2, 1, 0), if (nl) { VMCNT4; } else { VMCNT0; });
        PHASE(1, 0, if (nl) stageA(k2, 0, 0), );
        PHASE(1, 1, if (nl) stageA(k2, 1, 0), );
        PHASE(1, 2, if (nl) stageB(k3, 0, 1), );
        PHASE(1, 3, if (nl) stageB(k3, 1, 1), if (nl) { VMCNT4; });
    }
#undef PHASE

    const ll coff = (ll)bz * batchC;
    float s4[4] = {0.f, 0.f, 0.f, 0.f};
    #pragma unroll
    for (int fi = 0; fi < 8; ++fi)
    #pragma unroll
    for (int j = 0; j < 4; ++j)
    #pragma unroll
    for (int r4 = 0; r4 < 4; ++r4) {
        const int row = row0 + wrm*128 + fi*16 + fq*4 + r4;
        const int col = col0 + wcn*64 + j*16 + fr;
        float v = acc[fi][j][r4];
        if (OP == 0) {
            v += bias[col];
            ((__bf16*)Cp)[coff + (ll)row * ldc + col] = (__bf16)v;
        } else if (OP == 1) {
            float e = (msk && col > row) ? 0.f : __expf(v * 0.03125f);
            __bf16 eb = (__bf16)e;
            ((__bf16*)Cp)[coff + (ll)row * ldc + col] = eb;
            s4[j] += (float)eb;
        } else {
            ((float*)Cp)[coff + (ll)row * ldc + col] = v;
        }
    }
    if (OP == 1 && part != nullptr) {
        float* red = (float*)&LA[0][0][0];
        __syncthreads();
        #pragma unroll
        for (int j = 0; j < 4; ++j)
            red[(wrm*4 + fq)*256 + wcn*64 + j*16 + fr] = s4[j];
        __syncthreads();
        if (t < 256) {
            float tot = 0.f;
            #pragma unroll
            for (int r = 0; r < 8; ++r) tot += red[r*256 + t];
            part[((ll)bx * 8 + bz) * 2048 + col0 + t] = tot;
        }
    }
}

// ---------------------------------------------------------------------------
// PV (round-17 config — best measured, frozen).
// BM=64/BN=256, 2 blocks/CU, interleaved attn slices w/ masked fast path.
// ---------------------------------------------------------------------------
__global__ __launch_bounds__(512) void pv64(
    const __bf16* __restrict__ E, const __bf16* __restrict__ VT,
    const float* __restrict__ inv, float* __restrict__ out,
    float* __restrict__ attn, const int* __restrict__ maskp)
{
    __shared__ __bf16 LA[2][64][64];     // 16 KB
    __shared__ __bf16 LB[2][256][64];    // 64 KB

    const int n   = blockIdx.x;
    const int by  = n & 3;
    const int bxr = 31 - (n >> 2);       // longest first
    const int bz  = blockIdx.z;
    const int t = threadIdx.x, w = t >> 6, lane = t & 63;
    const int wrm = w >> 2, wcn = w & 3;
    const int fr = lane & 15, fq = lane >> 4;
    const int row0 = bxr * 64, col0 = by * 256;
    const int msk = maskp[0];

    int NT = msk ? ((bxr + 2) & ~1) : 32;
    const int NI = NT / 2;

    const __bf16* Ab = E  + (ll)bz * 2048 * 2048;
    const __bf16* Bb = VT + (ll)bz * 1024 * 2048;

    // attn-slice setup: cols by*512..+512, rows row0..+64 (8 slices x 8 rows)
    const int c0 = by * 512;
    const int ct = (t & 63) * 8;
    const int r00 = t >> 6;              // 0..7
    f32x4 ivlo = *(const f32x4*)&inv[bz*2048 + c0 + ct];
    f32x4 ivhi = *(const f32x4*)&inv[bz*2048 + c0 + ct + 4];

    auto slice = [&](int s) {
        const int row = row0 + s*8 + r00;
        float* ao = attn + (ll)bz*2048*2048 + (ll)row*2048 + c0 + ct;
        if (msk && c0 > row0 + s*8 + 7) {      // whole slice above diagonal
            f32x4 z = {};
            ((f32x4*)ao)[0] = z;
            ((f32x4*)ao)[1] = z;
            return;
        }
        bf16x8 ev = *(const bf16x8*)&Ab[(ll)row*2048 + c0 + ct];
        f32x4 lo, hi;
        #pragma unroll
        for (int e = 0; e < 4; ++e) {
            lo[e] = (float)ev[e]     * ivlo[e];
            hi[e] = (float)ev[e + 4] * ivhi[e];
        }
        ((f32x4*)ao)[0] = lo;
        ((f32x4*)ao)[1] = hi;
    };

    const int srow = lane >> 3;
    const int cg   = (lane & 7) ^ srow;

    auto stageA = [&](int kt, int slot) {
        GLD(Ab + (ll)(row0 + w*8 + srow) * 2048 + kt*64 + cg*8,
            &LA[slot][w*8][0]);
    };
    auto stageB = [&](int kt, int slot) {
        #pragma unroll
        for (int h = 0; h < 2; ++h)
        #pragma unroll
        for (int is = 0; is < 2; ++is)
            GLD(Bb + (ll)(col0 + h*128 + is*64 + w*8 + srow) * 2048 + kt*64 + cg*8,
                &LB[slot][h*128 + is*64 + w*8][0]);
    };
    auto rdA = [&](int slot, int row, int g) -> bf16x8 {
        return *(const bf16x8*)&LA[slot][row][(g ^ (row & 7)) << 3];
    };
    auto rdB = [&](int slot, int row, int g) -> bf16x8 {
        return *(const bf16x8*)&LB[slot][row][(g ^ (row & 7)) << 3];
    };

    f32x4  acc[2][4] = {};
    bf16x8 bB[4][2];

    // prologue
    stageA(0, 0); stageB(0, 0);
    stageB(1, 1);
    VMCNT4;
    SBAR();

#define PHASEP(SLOT, Q, STG, VMC) \
  { \
    if (Q == 0) { \
      _Pragma("unroll") for (int j = 0; j < 4; ++j) \
      _Pragma("unroll") for (int ks = 0; ks < 2; ++ks) \
        bB[j][ks] = rdB(SLOT, wcn*64 + j*16 + fr, ks*4 + fq); \
    } \
    bf16x8 bA[2]; \
    _Pragma("unroll") for (int ks = 0; ks < 2; ++ks) \
      bA[ks] = rdA(SLOT, wrm*32 + Q*16 + fr, ks*4 + fq); \
    STG; \
    VMC; \
    SBAR(); SCHED0(); \
    __builtin_amdgcn_s_setprio(1); \
    _Pragma("unroll") for (int j = 0; j < 4; ++j) \
    _Pragma("unroll") for (int ks = 0; ks < 2; ++ks) \
      acc[Q][j] = __builtin_amdgcn_mfma_f32_16x16x32_bf16( \
          bA[ks], bB[j][ks], acc[Q][j], 0, 0, 0); \
    __builtin_amdgcn_s_setprio(0); \
    SCHED0(); SBAR(); \
  }

    for (int i = 0; i < NI; ++i) {
        const bool nl = (i < NI - 1);
        const int kb = 2*i + 1, ka2 = 2*i + 2, kb2 = 2*i + 3;
        PHASEP(0, 0, stageA(kb, 1), );
        PHASEP(0, 1, if (nl) stageB(ka2, 0),
                     if (nl) { VMCNT4; } else { VMCNT0; });
        PHASEP(1, 0, if (nl) stageA(ka2, 0), );
        PHASEP(1, 1, if (nl) stageB(kb2, 1),
                     if (nl) { VMCNT4; });
        if (i < 8) slice(i);             // overlapped attn write
    }
#undef PHASEP

    // remaining attn slices (short-K blocks)
    for (int s = (NI < 8 ? NI : 8); s < 8; ++s) slice(s);

    // out stores
    #pragma unroll
    for (int qf = 0; qf < 2; ++qf)
    #pragma unroll
    for (int j = 0; j < 4; ++j)
    #pragma unroll
    for (int r4 = 0; r4 < 4; ++r4) {
        const int row = row0 + wrm*32 + qf*16 + fq*4 + r4;
        const int col = col0 + wcn*64 + j*16 + fr;
        out[(ll)bz*2048*1024 + (ll)row*1024 + col] = acc[qf][j][r4];
    }
}

// ---------------------------------------------------------------------------
// All input conversions in ONE launch.
// Blocks [0,8192): X -> Xb ; [8192,8704): Wq ; [8704,9216): Wk ;
// [9216,9728): Wv ; [9728,9740): bias concat. Grid 9740 x 256.
// ---------------------------------------------------------------------------
__global__ __launch_bounds__(256) void cvtall_k(
    const float* __restrict__ X,  const float* __restrict__ Wq,
    const float* __restrict__ Wk, const float* __restrict__ Wv,
    const float* __restrict__ bq, const float* __restrict__ bk,
    const float* __restrict__ bv,
    __bf16* __restrict__ Xb, __bf16* __restrict__ Wb, float* __restrict__ bb)
{
    const int b = blockIdx.x;
    if (b < 9728) {
        const float* src;
        __bf16* dst;
        ll i;
        if (b < 8192)      { src = X;  dst = Xb;             i = (ll)b * 256 + threadIdx.x; }
        else if (b < 8704) { src = Wq; dst = Wb;             i = (ll)(b - 8192) * 256 + threadIdx.x; }
        else if (b < 9216) { src = Wk; dst = Wb + 1024*1024; i = (ll)(b - 8704) * 256 + threadIdx.x; }
        else               { src = Wv; dst = Wb + 2048*1024; i = (ll)(b - 9216) * 256 + threadIdx.x; }
        const f32x4* p = (const f32x4*)(src + i * 8);
        f32x4 a = p[0], c = p[1];
        bf16x8 h;
        #pragma unroll
        for (int j = 0; j < 4; ++j) { h[j] = (__bf16)a[j]; h[j + 4] = (__bf16)c[j]; }
        *(bf16x8*)(dst + i * 8) = h;
    } else {
        const int i = (b - 9728) * 256 + threadIdx.x;   // 0..3071
        bb[i] = (i < 1024) ? bq[i] : (i < 2048) ? bk[i - 1024] : bv[i - 2048];
    }
}

// ---------------------------------------------------------------------------
// vtpf: V' transpose with INLINE colsum reduction (r19: rsum fused away).
// inv computed per-m from part (L2-hot, 512KB); k0==0 blocks publish inv[]
// (lane t&7==0 only -> each m written once; deterministic).
// ---------------------------------------------------------------------------
__global__ __launch_bounds__(256) void vtpf_k(const __bf16* __restrict__ qkv,
                                              const float* __restrict__ part,
                                              float* __restrict__ inv,
                                              __bf16* __restrict__ vt)
{
    __shared__ __bf16 tile[64][72];
    const int t  = threadIdx.x;
    const int m0 = blockIdx.x * 64;
    const int k0 = blockIdx.y * 64;
    const int b  = blockIdx.z;

    const __bf16* V = qkv + (ll)b * 2048 * 3072 + 2048;
    #pragma unroll
    for (int h = 0; h < 2; ++h) {
        int r = (t >> 3) + h * 32;
        int c = (t & 7) * 8;
        int m = m0 + r;
        float s = 0.f;
        #pragma unroll
        for (int lc = 0; lc < 8; ++lc) s += part[((ll)lc * 8 + b) * 2048 + m];
        const float iv = 1.0f / s;
        if (k0 == 0 && (t & 7) == 0) inv[b * 2048 + m] = iv;
        bf16x8 v = *(const bf16x8*)&V[(ll)m * 3072 + k0 + c];
        bf16x8 o;
        #pragma unroll
        for (int j = 0; j < 8; ++j) o[j] = (__bf16)((float)v[j] * iv);
        *(bf16x8*)&tile[r][c] = o;
    }
    __syncthreads();
    __bf16* O = vt + (ll)b * 1024 * 2048;
    #pragma unroll
    for (int h = 0; h < 2; ++h) {
        int k = (t >> 3) + h * 32;
        int m = (t & 7) * 8;
        bf16x8 o;
        #pragma unroll
        for (int j = 0; j < 8; ++j) o[j] = tile[m + j][k];
        *(bf16x8*)&O[(ll)(k0 + k) * 2048 + m0 + m] = o;
    }
}

// plain V transpose (fallback path)
__global__ __launch_bounds__(256) void vt_k(const unsigned short* __restrict__ qkv,
                                            unsigned short* __restrict__ vt)
{
    __shared__ unsigned short tile[64][72];
    const int t  = threadIdx.x;
    const int m0 = blockIdx.x * 64;
    const int k0 = blockIdx.y * 64;
    const int b  = blockIdx.z;

    const unsigned short* V = qkv + (ll)b * 2048 * 3072 + 2048;
    #pragma unroll
    for (int h = 0; h < 2; ++h) {
        int r = (t >> 3) + h * 32;
        int c = (t & 7) * 8;
        us8 v = *(const us8*)&V[(ll)(m0 + r) * 3072 + k0 + c];
        *(us8*)&tile[r][c] = v;
    }
    __syncthreads();
    unsigned short* O = vt + (ll)b * 1024 * 2048;
    #pragma unroll
    for (int h = 0; h < 2; ++h) {
        int k = (t >> 3) + h * 32;
        int m = (t & 7) * 8;
        us8 o;
        #pragma unroll
        for (int j = 0; j < 8; ++j) o[j] = tile[m + j][k];
        *(us8*)&O[(ll)(k0 + k) * 2048 + m0 + m] = o;
    }
}

// fallback-path aux
__global__ __launch_bounds__(256) void colsum_k(const __bf16* __restrict__ E,
                                                float* __restrict__ part)
{
    const int lc = blockIdx.x, mc = blockIdx.y, b = blockIdx.z;
    const int m  = mc * 256 + threadIdx.x;
    const __bf16* p = E + (ll)b * 2048 * 2048 + (ll)(lc * 256) * 2048 + m;
    float s = 0.f;
    #pragma unroll 4
    for (int l = 0; l < 256; ++l) s += (float)p[(ll)l * 2048];
    part[((ll)lc * 8 + b) * 2048 + m] = s;
}

__global__ __launch_bounds__(256) void norm_k(const __bf16* __restrict__ E,
                                              const float* __restrict__ part,
                                              float* __restrict__ attn,
                                              __bf16* __restrict__ attn_bf)
{
    const int lc = blockIdx.x, mc = blockIdx.y, b = blockIdx.z;
    const int m  = mc * 256 + threadIdx.x;
    float s = 0.f;
    #pragma unroll
    for (int j = 0; j < 8; ++j) s += part[((ll)j * 8 + b) * 2048 + m];
    const float iv = 1.0f / s;
    const __bf16* p = E + (ll)b * 2048 * 2048 + (ll)(lc * 256) * 2048 + m;
    float*  qo = attn    + (ll)b * 2048 * 2048 + (ll)(lc * 256) * 2048 + m;
    __bf16* ro = attn_bf + (ll)b * 2048 * 2048 + (ll)(lc * 256) * 2048 + m;
    #pragma unroll 4
    for (int l = 0; l < 256; ++l) {
        float a = (float)p[(ll)l * 2048] * iv;
        qo[(ll)l * 2048] = a;
        ro[(ll)l * 2048] = (__bf16)a;
    }
}

// ---------------------------------------------------------------------------
extern "C" void kernel_launch(void* const* d_in, const int* in_sizes, int n_in,
                              void* d_out, int out_size, void* d_ws, size_t ws_size,
                              hipStream_t stream)
{
    const float* X   = (const float*)d_in[0];
    const float* Wq  = (const float*)d_in[1];
    const float* bq  = (const float*)d_in[2];
    const float* Wk  = (const float*)d_in[3];
    const float* bk  = (const float*)d_in[4];
    const float* Wv  = (const float*)d_in[5];
    const float* bv  = (const float*)d_in[6];
    const int*   msk = (const int*)d_in[7];

    float* out  = (float*)d_out;                  // (8,2048,1024) fp32
    float* attn = out + (ll)8 * 2048 * 1024;      // (8,2048,2048) fp32

    __bf16* Xb = (__bf16*)attn;                   // staging in attn region
    __bf16* Wb = Xb + (ll)16384 * 1024;
    float*  bb = (float*)(Wb + (ll)3072 * 1024);

    __bf16* qkv = (__bf16*)d_ws;                  // 96 MiB
    __bf16* vt  = qkv + (ll)16384 * 3072;         // 32 MiB

    // 0) all bf16 conversions in one launch
    cvtall_k<<<dim3(9740), 256, 0, stream>>>(X, Wq, Wk, Wv, bq, bk, bv,
                                             Xb, Wb, bb);

    // 1) QKV projection
    gemm8<0><<<dim3(64, 12, 1), 512, 0, stream>>>(
        Xb, Wb, qkv, bb, msk, nullptr,
        1024, 1024, 1024, 3072, 0LL, 0LL, 0LL);

    const size_t need_fused =
        (size_t)(16384ll*3072 + 8ll*1024*2048 + 8ll*2048*2048) * 2
        + (size_t)(8*8*2048 + 8*2048) * 4;

    if (ws_size >= need_fused) {
        // fused path: E in ws, inv folded into V^T, attn fused into PV
        __bf16* E   = vt + (ll)8 * 1024 * 2048;
        float*  prt = (float*)(E + (ll)8 * 2048 * 2048);
        float*  inv = prt + 8 * 8 * 2048;

        // 2) E = exp(QK^T/32, masked) -> ws; fused column partial sums
        gemm8<1><<<dim3(8, 8, 8), 512, 0, stream>>>(
            qkv, qkv + 1024, E, nullptr, msk, prt,
            1024, 3072, 3072, 2048,
            (ll)2048 * 3072, (ll)2048 * 3072, (ll)2048 * 2048);

        // 3) vt = (V * inv)^T with inline colsum reduce; publishes inv[]
        vtpf_k<<<dim3(32, 16, 8), 256, 0, stream>>>(qkv, prt, inv, vt);

        // 4) out = E @ vt^T  +  attn = E*inv interleaved (masked fast path)
        pv64<<<dim3(128, 1, 8), 512, 0, stream>>>(E, vt, inv, out, attn, msk);
    } else {
        // fallback: round-4 proven pipeline
        __bf16* E   = (__bf16*)d_out;
        float*  prt = (float*)(vt + (ll)8 * 1024 * 2048);
        __bf16* attn_bf = qkv;

        vt_k<<<dim3(32, 16, 8), 256, 0, stream>>>((const unsigned short*)qkv,
                                                  (unsigned short*)vt);

        gemm8<1><<<dim3(8, 8, 8), 512, 0, stream>>>(
            qkv, qkv + 1024, E, nullptr, msk, nullptr,
            1024, 3072, 3072, 2048,
            (ll)2048 * 3072, (ll)2048 * 3072, (ll)2048 * 2048);

        colsum_k<<<dim3(8, 8, 8), 256, 0, stream>>>(E, prt);
        norm_k<<<dim3(8, 8, 8), 256, 0, stream>>>(E, prt, attn, attn_bf);

        gemm8<2><<<dim3(8, 4, 8), 512, 0, stream>>>(
            attn_bf, vt, out, nullptr, msk, nullptr,
            2048, 2048, 2048, 1024,
            (ll)2048 * 2048, (ll)1024 * 2048, (ll)2048 * 1024);
    }
}

// Round 20
// 299.437 us; speedup vs baseline: 1.0675x; 1.0405x over previous
//
#include <hip/hip_runtime.h>
#include <hip/hip_bf16.h>

typedef __attribute__((ext_vector_type(8))) __bf16 bf16x8;
typedef __attribute__((ext_vector_type(8))) unsigned short us8;
typedef __attribute__((ext_vector_type(4))) float f32x4;
typedef long long ll;

#define GLD(gp, lp) __builtin_amdgcn_global_load_lds( \
    (const __attribute__((address_space(1))) void*)(gp), \
    (__attribute__((address_space(3))) void*)(lp), 16, 0, 0)

#define SBAR()  asm volatile("s_barrier" ::: "memory")
#define VMCNT4  asm volatile("s_waitcnt vmcnt(4)" ::: "memory")
#define VMCNT0  asm volatile("s_waitcnt vmcnt(0)" ::: "memory")
#define SCHED0() __builtin_amdgcn_sched_barrier(0)

// ---------------------------------------------------------------------------
// 256x256-tile 8-phase GEMM (round-17/19 config — best measured, frozen).
// OP 0: proj C=bf16 (+bias)
// OP 1: scores C=bf16 exp(v/32, masked; dead tiles by-bx>=3 elided);
//        fused col-sums -> part; diagonal-tile wave skip.
// OP 2: PV (fallback path only)
// ---------------------------------------------------------------------------
template<int OP>
__global__ __launch_bounds__(512) void gemm8(
    const __bf16* __restrict__ A, const __bf16* __restrict__ B,
    void* __restrict__ Cp, const float* __restrict__ bias,
    const int* __restrict__ maskp, float* __restrict__ part,
    int K, int lda, int ldb, int ldc,
    ll batchA, ll batchB, ll batchC)
{
    __shared__ __bf16 LA[2][256][64];
    __shared__ __bf16 LB[2][256][64];

    const int bx = blockIdx.x, by = blockIdx.y, bz = blockIdx.z;
    const int t    = threadIdx.x;
    const int w    = t >> 6, lane = t & 63;
    const int wrm  = w >> 2, wcn  = w & 3;
    const int fr   = lane & 15, fq = lane >> 4;
    const int row0 = bx * 256;
    const int col0 = by * 256;
    const int msk  = (OP >= 1) ? maskp[0] : 0;

    if (OP == 1 && msk && by > bx) {
        if (part && t < 256) part[((ll)bx * 8 + bz) * 2048 + col0 + t] = 0.f;
        if (by - bx >= 3) return;              // dead tile: never read
        __bf16* C = (__bf16*)Cp + (ll)bz * batchC;
        bf16x8 z = {};
        #pragma unroll 4
        for (int pass = 0; pass < 16; ++pass) {
            int r = pass * 16 + (t >> 5);
            *(bf16x8*)&C[(ll)(row0 + r) * ldc + col0 + (t & 31) * 8] = z;
        }
        return;
    }

    // wave-level skip: diagonal tiles, quadrant entirely above diagonal
    const bool wskip = (OP == 1) && msk && (by == bx) && (wcn * 64 > wrm * 128 + 127);

    int NT = K / 64;
    if (OP == 2 && msk) NT = (row0 + 256) / 64;
    const int NI = NT / 2;

    const __bf16* Ab = A + (ll)bz * batchA;
    const __bf16* Bb = B + (ll)bz * batchB;

    const int srow = lane >> 3;
    const int cg   = (lane & 7) ^ srow;

    auto stageA = [&](int kt, int h, int slot) {
        #pragma unroll
        for (int is = 0; is < 2; ++is)
            GLD(Ab + (ll)(row0 + h*128 + is*64 + w*8 + srow) * lda + kt*64 + cg*8,
                &LA[slot][h*128 + is*64 + w*8][0]);
    };
    auto stageB = [&](int kt, int h, int slot) {
        #pragma unroll
        for (int is = 0; is < 2; ++is)
            GLD(Bb + (ll)(col0 + h*128 + is*64 + w*8 + srow) * ldb + kt*64 + cg*8,
                &LB[slot][h*128 + is*64 + w*8][0]);
    };
    auto rdA = [&](int slot, int row, int g) -> bf16x8 {
        return *(const bf16x8*)&LA[slot][row][(g ^ (row & 7)) << 3];
    };
    auto rdB = [&](int slot, int row, int g) -> bf16x8 {
        return *(const bf16x8*)&LB[slot][row][(g ^ (row & 7)) << 3];
    };

    f32x4  acc[8][4] = {};
    bf16x8 bB[4][2];

    stageA(0, 0, 0); stageA(0, 1, 0);
    stageB(0, 0, 0); stageB(0, 1, 0);
    stageB(1, 0, 1); stageB(1, 1, 1);
    VMCNT4;
    SBAR();

#define PHASE(SLOT, Q, STG, VMC) \
  { \
    if (Q == 0) { \
      _Pragma("unroll") for (int j = 0; j < 4; ++j) \
      _Pragma("unroll") for (int ks = 0; ks < 2; ++ks) \
        bB[j][ks] = rdB(SLOT, wcn*64 + j*16 + fr, ks*4 + fq); \
    } \
    bf16x8 bA[2][2]; \
    _Pragma("unroll") for (int fi = 0; fi < 2; ++fi) \
    _Pragma("unroll") for (int ks = 0; ks < 2; ++ks) \
      bA[fi][ks] = rdA(SLOT, wrm*128 + (Q*2+fi)*16 + fr, ks*4 + fq); \
    STG; \
    VMC; \
    SBAR(); SCHED0(); \
    if (!wskip) { \
      __builtin_amdgcn_s_setprio(1); \
      _Pragma("unroll") for (int fi = 0; fi < 2; ++fi) \
      _Pragma("unroll") for (int j = 0; j < 4; ++j) \
      _Pragma("unroll") for (int ks = 0; ks < 2; ++ks) \
        acc[Q*2+fi][j] = __builtin_amdgcn_mfma_f32_16x16x32_bf16( \
            bA[fi][ks], bB[j][ks], acc[Q*2+fi][j], 0, 0, 0); \
      __builtin_amdgcn_s_setprio(0); \
    } \
    SCHED0(); SBAR(); \
  }

    for (int i = 0; i < NI; ++i) {
        const bool nl = (i < NI - 1);
        const int k1 = 2*i + 1, k2 = 2*i + 2, k3 = 2*i + 3;
        PHASE(0, 0, stageA(k1, 0, 1), );
        PHASE(0, 1, stageA(k1, 1, 1), );
        PHASE(0, 2, if (nl) stageB(k2, 0, 0), );
        PHASE(0, 3, if (nl) stageB(k2, 1, 0), if (nl) { VMCNT4; } else { VMCNT0; });
        PHASE(1, 0, if (nl) stageA(k2, 0, 0), );
        PHASE(1, 1, if (nl) stageA(k2, 1, 0), );
        PHASE(1, 2, if (nl) stageB(k3, 0, 1), );
        PHASE(1, 3, if (nl) stageB(k3, 1, 1), if (nl) { VMCNT4; });
    }
#undef PHASE

    const ll coff = (ll)bz * batchC;
    float s4[4] = {0.f, 0.f, 0.f, 0.f};
    #pragma unroll
    for (int fi = 0; fi < 8; ++fi)
    #pragma unroll
    for (int j = 0; j < 4; ++j)
    #pragma unroll
    for (int r4 = 0; r4 < 4; ++r4) {
        const int row = row0 + wrm*128 + fi*16 + fq*4 + r4;
        const int col = col0 + wcn*64 + j*16 + fr;
        float v = acc[fi][j][r4];
        if (OP == 0) {
            v += bias[col];
            ((__bf16*)Cp)[coff + (ll)row * ldc + col] = (__bf16)v;
        } else if (OP == 1) {
            float e = (msk && col > row) ? 0.f : __expf(v * 0.03125f);
            __bf16 eb = (__bf16)e;
            ((__bf16*)Cp)[coff + (ll)row * ldc + col] = eb;
            s4[j] += (float)eb;
        } else {
            ((float*)Cp)[coff + (ll)row * ldc + col] = v;
        }
    }
    if (OP == 1 && part != nullptr) {
        float* red = (float*)&LA[0][0][0];
        __syncthreads();
        #pragma unroll
        for (int j = 0; j < 4; ++j)
            red[(wrm*4 + fq)*256 + wcn*64 + j*16 + fr] = s4[j];
        __syncthreads();
        if (t < 256) {
            float tot = 0.f;
            #pragma unroll
            for (int r = 0; r < 8; ++r) tot += red[r*256 + t];
            part[((ll)bx * 8 + bz) * 2048 + col0 + t] = tot;
        }
    }
}

// ---------------------------------------------------------------------------
// PV (round-17 config) + r20: bijective chunked XCD swizzle on the flattened
// 1024-block grid. Mechanism: the 4 by-siblings sharing each 256KB E strip
// were round-robined onto 4 DIFFERENT XCDs (private L2s) -> E fetched ~4x
// from HBM. Chunked remap (swz = (f&7)*128 + f/8) gives each XCD one
// contiguous chunk (= one batch); siblings become same-XCD neighbors.
// Longest-first preserved within each chunk. Index-only change.
// ---------------------------------------------------------------------------
__global__ __launch_bounds__(512) void pv64(
    const __bf16* __restrict__ E, const __bf16* __restrict__ VT,
    const float* __restrict__ inv, float* __restrict__ out,
    float* __restrict__ attn, const int* __restrict__ maskp)
{
    __shared__ __bf16 LA[2][64][64];     // 16 KB
    __shared__ __bf16 LB[2][256][64];    // 64 KB

    // chunked XCD swizzle over flat [0,1024)
    const int f   = (int)blockIdx.x + 128 * (int)blockIdx.z;
    const int swz = (f & 7) * 128 + (f >> 3);
    const int n   = swz & 127;
    const int bz  = swz >> 7;
    const int by  = n & 3;
    const int bxr = 31 - (n >> 2);       // longest first within chunk
    const int t = threadIdx.x, w = t >> 6, lane = t & 63;
    const int wrm = w >> 2, wcn = w & 3;
    const int fr = lane & 15, fq = lane >> 4;
    const int row0 = bxr * 64, col0 = by * 256;
    const int msk = maskp[0];

    int NT = msk ? ((bxr + 2) & ~1) : 32;
    const int NI = NT / 2;

    const __bf16* Ab = E  + (ll)bz * 2048 * 2048;
    const __bf16* Bb = VT + (ll)bz * 1024 * 2048;

    // attn-slice setup: cols by*512..+512, rows row0..+64 (8 slices x 8 rows)
    const int c0 = by * 512;
    const int ct = (t & 63) * 8;
    const int r00 = t >> 6;              // 0..7
    f32x4 ivlo = *(const f32x4*)&inv[bz*2048 + c0 + ct];
    f32x4 ivhi = *(const f32x4*)&inv[bz*2048 + c0 + ct + 4];

    auto slice = [&](int s) {
        const int row = row0 + s*8 + r00;
        float* ao = attn + (ll)bz*2048*2048 + (ll)row*2048 + c0 + ct;
        if (msk && c0 > row0 + s*8 + 7) {      // whole slice above diagonal
            f32x4 z = {};
            ((f32x4*)ao)[0] = z;
            ((f32x4*)ao)[1] = z;
            return;
        }
        bf16x8 ev = *(const bf16x8*)&Ab[(ll)row*2048 + c0 + ct];
        f32x4 lo, hi;
        #pragma unroll
        for (int e = 0; e < 4; ++e) {
            lo[e] = (float)ev[e]     * ivlo[e];
            hi[e] = (float)ev[e + 4] * ivhi[e];
        }
        ((f32x4*)ao)[0] = lo;
        ((f32x4*)ao)[1] = hi;
    };

    const int srow = lane >> 3;
    const int cg   = (lane & 7) ^ srow;

    auto stageA = [&](int kt, int slot) {
        GLD(Ab + (ll)(row0 + w*8 + srow) * 2048 + kt*64 + cg*8,
            &LA[slot][w*8][0]);
    };
    auto stageB = [&](int kt, int slot) {
        #pragma unroll
        for (int h = 0; h < 2; ++h)
        #pragma unroll
        for (int is = 0; is < 2; ++is)
            GLD(Bb + (ll)(col0 + h*128 + is*64 + w*8 + srow) * 2048 + kt*64 + cg*8,
                &LB[slot][h*128 + is*64 + w*8][0]);
    };
    auto rdA = [&](int slot, int row, int g) -> bf16x8 {
        return *(const bf16x8*)&LA[slot][row][(g ^ (row & 7)) << 3];
    };
    auto rdB = [&](int slot, int row, int g) -> bf16x8 {
        return *(const bf16x8*)&LB[slot][row][(g ^ (row & 7)) << 3];
    };

    f32x4  acc[2][4] = {};
    bf16x8 bB[4][2];

    // prologue
    stageA(0, 0); stageB(0, 0);
    stageB(1, 1);
    VMCNT4;
    SBAR();

#define PHASEP(SLOT, Q, STG, VMC) \
  { \
    if (Q == 0) { \
      _Pragma("unroll") for (int j = 0; j < 4; ++j) \
      _Pragma("unroll") for (int ks = 0; ks < 2; ++ks) \
        bB[j][ks] = rdB(SLOT, wcn*64 + j*16 + fr, ks*4 + fq); \
    } \
    bf16x8 bA[2]; \
    _Pragma("unroll") for (int ks = 0; ks < 2; ++ks) \
      bA[ks] = rdA(SLOT, wrm*32 + Q*16 + fr, ks*4 + fq); \
    STG; \
    VMC; \
    SBAR(); SCHED0(); \
    __builtin_amdgcn_s_setprio(1); \
    _Pragma("unroll") for (int j = 0; j < 4; ++j) \
    _Pragma("unroll") for (int ks = 0; ks < 2; ++ks) \
      acc[Q][j] = __builtin_amdgcn_mfma_f32_16x16x32_bf16( \
          bA[ks], bB[j][ks], acc[Q][j], 0, 0, 0); \
    __builtin_amdgcn_s_setprio(0); \
    SCHED0(); SBAR(); \
  }

    for (int i = 0; i < NI; ++i) {
        const bool nl = (i < NI - 1);
        const int kb = 2*i + 1, ka2 = 2*i + 2, kb2 = 2*i + 3;
        PHASEP(0, 0, stageA(kb, 1), );
        PHASEP(0, 1, if (nl) stageB(ka2, 0),
                     if (nl) { VMCNT4; } else { VMCNT0; });
        PHASEP(1, 0, if (nl) stageA(ka2, 0), );
        PHASEP(1, 1, if (nl) stageB(kb2, 1),
                     if (nl) { VMCNT4; });
        if (i < 8) slice(i);             // overlapped attn write
    }
#undef PHASEP

    // remaining attn slices (short-K blocks)
    for (int s = (NI < 8 ? NI : 8); s < 8; ++s) slice(s);

    // out stores
    #pragma unroll
    for (int qf = 0; qf < 2; ++qf)
    #pragma unroll
    for (int j = 0; j < 4; ++j)
    #pragma unroll
    for (int r4 = 0; r4 < 4; ++r4) {
        const int row = row0 + wrm*32 + qf*16 + fq*4 + r4;
        const int col = col0 + wcn*64 + j*16 + fr;
        out[(ll)bz*2048*1024 + (ll)row*1024 + col] = acc[qf][j][r4];
    }
}

// ---------------------------------------------------------------------------
// All input conversions in ONE launch.
// ---------------------------------------------------------------------------
__global__ __launch_bounds__(256) void cvtall_k(
    const float* __restrict__ X,  const float* __restrict__ Wq,
    const float* __restrict__ Wk, const float* __restrict__ Wv,
    const float* __restrict__ bq, const float* __restrict__ bk,
    const float* __restrict__ bv,
    __bf16* __restrict__ Xb, __bf16* __restrict__ Wb, float* __restrict__ bb)
{
    const int b = blockIdx.x;
    if (b < 9728) {
        const float* src;
        __bf16* dst;
        ll i;
        if (b < 8192)      { src = X;  dst = Xb;             i = (ll)b * 256 + threadIdx.x; }
        else if (b < 8704) { src = Wq; dst = Wb;             i = (ll)(b - 8192) * 256 + threadIdx.x; }
        else if (b < 9216) { src = Wk; dst = Wb + 1024*1024; i = (ll)(b - 8704) * 256 + threadIdx.x; }
        else               { src = Wv; dst = Wb + 2048*1024; i = (ll)(b - 9216) * 256 + threadIdx.x; }
        const f32x4* p = (const f32x4*)(src + i * 8);
        f32x4 a = p[0], c = p[1];
        bf16x8 h;
        #pragma unroll
        for (int j = 0; j < 4; ++j) { h[j] = (__bf16)a[j]; h[j + 4] = (__bf16)c[j]; }
        *(bf16x8*)(dst + i * 8) = h;
    } else {
        const int i = (b - 9728) * 256 + threadIdx.x;   // 0..3071
        bb[i] = (i < 1024) ? bq[i] : (i < 2048) ? bk[i - 1024] : bv[i - 2048];
    }
}

// ---------------------------------------------------------------------------
// vtpf: V' transpose with INLINE colsum reduction; publishes inv[].
// ---------------------------------------------------------------------------
__global__ __launch_bounds__(256) void vtpf_k(const __bf16* __restrict__ qkv,
                                              const float* __restrict__ part,
                                              float* __restrict__ inv,
                                              __bf16* __restrict__ vt)
{
    __shared__ __bf16 tile[64][72];
    const int t  = threadIdx.x;
    const int m0 = blockIdx.x * 64;
    const int k0 = blockIdx.y * 64;
    const int b  = blockIdx.z;

    const __bf16* V = qkv + (ll)b * 2048 * 3072 + 2048;
    #pragma unroll
    for (int h = 0; h < 2; ++h) {
        int r = (t >> 3) + h * 32;
        int c = (t & 7) * 8;
        int m = m0 + r;
        float s = 0.f;
        #pragma unroll
        for (int lc = 0; lc < 8; ++lc) s += part[((ll)lc * 8 + b) * 2048 + m];
        const float iv = 1.0f / s;
        if (k0 == 0 && (t & 7) == 0) inv[b * 2048 + m] = iv;
        bf16x8 v = *(const bf16x8*)&V[(ll)m * 3072 + k0 + c];
        bf16x8 o;
        #pragma unroll
        for (int j = 0; j < 8; ++j) o[j] = (__bf16)((float)v[j] * iv);
        *(bf16x8*)&tile[r][c] = o;
    }
    __syncthreads();
    __bf16* O = vt + (ll)b * 1024 * 2048;
    #pragma unroll
    for (int h = 0; h < 2; ++h) {
        int k = (t >> 3) + h * 32;
        int m = (t & 7) * 8;
        bf16x8 o;
        #pragma unroll
        for (int j = 0; j < 8; ++j) o[j] = tile[m + j][k];
        *(bf16x8*)&O[(ll)(k0 + k) * 2048 + m0 + m] = o;
    }
}

// plain V transpose (fallback path)
__global__ __launch_bounds__(256) void vt_k(const unsigned short* __restrict__ qkv,
                                            unsigned short* __restrict__ vt)
{
    __shared__ unsigned short tile[64][72];
    const int t  = threadIdx.x;
    const int m0 = blockIdx.x * 64;
    const int k0 = blockIdx.y * 64;
    const int b  = blockIdx.z;

    const unsigned short* V = qkv + (ll)b * 2048 * 3072 + 2048;
    #pragma unroll
    for (int h = 0; h < 2; ++h) {
        int r = (t >> 3) + h * 32;
        int c = (t & 7) * 8;
        us8 v = *(const us8*)&V[(ll)(m0 + r) * 3072 + k0 + c];
        *(us8*)&tile[r][c] = v;
    }
    __syncthreads();
    unsigned short* O = vt + (ll)b * 1024 * 2048;
    #pragma unroll
    for (int h = 0; h < 2; ++h) {
        int k = (t >> 3) + h * 32;
        int m = (t & 7) * 8;
        us8 o;
        #pragma unroll
        for (int j = 0; j < 8; ++j) o[j] = tile[m + j][k];
        *(us8*)&O[(ll)(k0 + k) * 2048 + m0 + m] = o;
    }
}

// fallback-path aux
__global__ __launch_bounds__(256) void colsum_k(const __bf16* __restrict__ E,
                                                float* __restrict__ part)
{
    const int lc = blockIdx.x, mc = blockIdx.y, b = blockIdx.z;
    const int m  = mc * 256 + threadIdx.x;
    const __bf16* p = E + (ll)b * 2048 * 2048 + (ll)(lc * 256) * 2048 + m;
    float s = 0.f;
    #pragma unroll 4
    for (int l = 0; l < 256; ++l) s += (float)p[(ll)l * 2048];
    part[((ll)lc * 8 + b) * 2048 + m] = s;
}

__global__ __launch_bounds__(256) void norm_k(const __bf16* __restrict__ E,
                                              const float* __restrict__ part,
                                              float* __restrict__ attn,
                                              __bf16* __restrict__ attn_bf)
{
    const int lc = blockIdx.x, mc = blockIdx.y, b = blockIdx.z;
    const int m  = mc * 256 + threadIdx.x;
    float s = 0.f;
    #pragma unroll
    for (int j = 0; j < 8; ++j) s += part[((ll)j * 8 + b) * 2048 + m];
    const float iv = 1.0f / s;
    const __bf16* p = E + (ll)b * 2048 * 2048 + (ll)(lc * 256) * 2048 + m;
    float*  qo = attn    + (ll)b * 2048 * 2048 + (ll)(lc * 256) * 2048 + m;
    __bf16* ro = attn_bf + (ll)b * 2048 * 2048 + (ll)(lc * 256) * 2048 + m;
    #pragma unroll 4
    for (int l = 0; l < 256; ++l) {
        float a = (float)p[(ll)l * 2048] * iv;
        qo[(ll)l * 2048] = a;
        ro[(ll)l * 2048] = (__bf16)a;
    }
}

// ---------------------------------------------------------------------------
extern "C" void kernel_launch(void* const* d_in, const int* in_sizes, int n_in,
                              void* d_out, int out_size, void* d_ws, size_t ws_size,
                              hipStream_t stream)
{
    const float* X   = (const float*)d_in[0];
    const float* Wq  = (const float*)d_in[1];
    const float* bq  = (const float*)d_in[2];
    const float* Wk  = (const float*)d_in[3];
    const float* bk  = (const float*)d_in[4];
    const float* Wv  = (const float*)d_in[5];
    const float* bv  = (const float*)d_in[6];
    const int*   msk = (const int*)d_in[7];

    float* out  = (float*)d_out;                  // (8,2048,1024) fp32
    float* attn = out + (ll)8 * 2048 * 1024;      // (8,2048,2048) fp32

    __bf16* Xb = (__bf16*)attn;                   // staging in attn region
    __bf16* Wb = Xb + (ll)16384 * 1024;
    float*  bb = (float*)(Wb + (ll)3072 * 1024);

    __bf16* qkv = (__bf16*)d_ws;                  // 96 MiB
    __bf16* vt  = qkv + (ll)16384 * 3072;         // 32 MiB

    // 0) all bf16 conversions in one launch
    cvtall_k<<<dim3(9740), 256, 0, stream>>>(X, Wq, Wk, Wv, bq, bk, bv,
                                             Xb, Wb, bb);

    // 1) QKV projection
    gemm8<0><<<dim3(64, 12, 1), 512, 0, stream>>>(
        Xb, Wb, qkv, bb, msk, nullptr,
        1024, 1024, 1024, 3072, 0LL, 0LL, 0LL);

    const size_t need_fused =
        (size_t)(16384ll*3072 + 8ll*1024*2048 + 8ll*2048*2048) * 2
        + (size_t)(8*8*2048 + 8*2048) * 4;

    if (ws_size >= need_fused) {
        // fused path: E in ws, inv folded into V^T, attn fused into PV
        __bf16* E   = vt + (ll)8 * 1024 * 2048;
        float*  prt = (float*)(E + (ll)8 * 2048 * 2048);
        float*  inv = prt + 8 * 8 * 2048;

        // 2) E = exp(QK^T/32, masked) -> ws; fused column partial sums
        gemm8<1><<<dim3(8, 8, 8), 512, 0, stream>>>(
            qkv, qkv + 1024, E, nullptr, msk, prt,
            1024, 3072, 3072, 2048,
            (ll)2048 * 3072, (ll)2048 * 3072, (ll)2048 * 2048);

        // 3) vt = (V * inv)^T with inline colsum reduce; publishes inv[]
        vtpf_k<<<dim3(32, 16, 8), 256, 0, stream>>>(qkv, prt, inv, vt);

        // 4) out = E @ vt^T + attn slices; chunked XCD swizzle for E reuse
        pv64<<<dim3(128, 1, 8), 512, 0, stream>>>(E, vt, inv, out, attn, msk);
    } else {
        // fallback: round-4 proven pipeline
        __bf16* E   = (__bf16*)d_out;
        float*  prt = (float*)(vt + (ll)8 * 1024 * 2048);
        __bf16* attn_bf = qkv;

        vt_k<<<dim3(32, 16, 8), 256, 0, stream>>>((const unsigned short*)qkv,
                                                  (unsigned short*)vt);

        gemm8<1><<<dim3(8, 8, 8), 512, 0, stream>>>(
            qkv, qkv + 1024, E, nullptr, msk, nullptr,
            1024, 3072, 3072, 2048,
            (ll)2048 * 3072, (ll)2048 * 3072, (ll)2048 * 2048);

        colsum_k<<<dim3(8, 8, 8), 256, 0, stream>>>(E, prt);
        norm_k<<<dim3(8, 8, 8), 256, 0, stream>>>(E, prt, attn, attn_bf);

        gemm8<2><<<dim3(8, 4, 8), 512, 0, stream>>>(
            attn_bf, vt, out, nullptr, msk, nullptr,
            2048, 2048, 2048, 1024,
            (ll)2048 * 2048, (ll)1024 * 2048, (ll)2048 * 1024);
    }
}

// Round 21
// 292.999 us; speedup vs baseline: 1.0909x; 1.0220x over previous
//
#include <hip/hip_runtime.h>
#include <hip/hip_bf16.h>

typedef __attribute__((ext_vector_type(8))) __bf16 bf16x8;
typedef __attribute__((ext_vector_type(8))) unsigned short us8;
typedef __attribute__((ext_vector_type(4))) float f32x4;
typedef long long ll;

#define GLD(gp, lp) __builtin_amdgcn_global_load_lds( \
    (const __attribute__((address_space(1))) void*)(gp), \
    (__attribute__((address_space(3))) void*)(lp), 16, 0, 0)

#define SBAR()  asm volatile("s_barrier" ::: "memory")
#define VMCNT4  asm volatile("s_waitcnt vmcnt(4)" ::: "memory")
#define VMCNT0  asm volatile("s_waitcnt vmcnt(0)" ::: "memory")
#define SCHED0() __builtin_amdgcn_sched_barrier(0)

// ---------------------------------------------------------------------------
// 256x256-tile 8-phase GEMM (round-17/19 config — best measured, frozen).
// OP 0: proj C=bf16 (+bias)
// OP 1: scores C=bf16 exp(v/32, masked; dead tiles by-bx>=3 elided);
//        fused col-sums -> part; diagonal-tile wave skip.
//        r21: chunked per-batch XCD swizzle (mechanism validated on pv64
//        r20: same-panel blocks must be same-XCD for L2 reuse).
// OP 2: PV (fallback path only)
// ---------------------------------------------------------------------------
template<int OP>
__global__ __launch_bounds__(512) void gemm8(
    const __bf16* __restrict__ A, const __bf16* __restrict__ B,
    void* __restrict__ Cp, const float* __restrict__ bias,
    const int* __restrict__ maskp, float* __restrict__ part,
    int K, int lda, int ldb, int ldc,
    ll batchA, ll batchB, ll batchC)
{
    __shared__ __bf16 LA[2][256][64];
    __shared__ __bf16 LB[2][256][64];

    int bx = blockIdx.x, by = blockIdx.y, bz = blockIdx.z;
    if (OP == 1) {
        // grid (8,8,8): each XCD gets one bz chunk; bx fastest within chunk
        const int f   = (int)blockIdx.x + 8 * (int)blockIdx.y + 64 * (int)blockIdx.z;
        const int swz = (f & 7) * 64 + (f >> 3);
        bx = swz & 7; by = (swz >> 3) & 7; bz = swz >> 6;
    }
    const int t    = threadIdx.x;
    const int w    = t >> 6, lane = t & 63;
    const int wrm  = w >> 2, wcn  = w & 3;
    const int fr   = lane & 15, fq = lane >> 4;
    const int row0 = bx * 256;
    const int col0 = by * 256;
    const int msk  = (OP >= 1) ? maskp[0] : 0;

    if (OP == 1 && msk && by > bx) {
        if (part && t < 256) part[((ll)bx * 8 + bz) * 2048 + col0 + t] = 0.f;
        if (by - bx >= 3) return;              // dead tile: never read
        __bf16* C = (__bf16*)Cp + (ll)bz * batchC;
        bf16x8 z = {};
        #pragma unroll 4
        for (int pass = 0; pass < 16; ++pass) {
            int r = pass * 16 + (t >> 5);
            *(bf16x8*)&C[(ll)(row0 + r) * ldc + col0 + (t & 31) * 8] = z;
        }
        return;
    }

    // wave-level skip: diagonal tiles, quadrant entirely above diagonal
    const bool wskip = (OP == 1) && msk && (by == bx) && (wcn * 64 > wrm * 128 + 127);

    int NT = K / 64;
    if (OP == 2 && msk) NT = (row0 + 256) / 64;
    const int NI = NT / 2;

    const __bf16* Ab = A + (ll)bz * batchA;
    const __bf16* Bb = B + (ll)bz * batchB;

    const int srow = lane >> 3;
    const int cg   = (lane & 7) ^ srow;

    auto stageA = [&](int kt, int h, int slot) {
        #pragma unroll
        for (int is = 0; is < 2; ++is)
            GLD(Ab + (ll)(row0 + h*128 + is*64 + w*8 + srow) * lda + kt*64 + cg*8,
                &LA[slot][h*128 + is*64 + w*8][0]);
    };
    auto stageB = [&](int kt, int h, int slot) {
        #pragma unroll
        for (int is = 0; is < 2; ++is)
            GLD(Bb + (ll)(col0 + h*128 + is*64 + w*8 + srow) * ldb + kt*64 + cg*8,
                &LB[slot][h*128 + is*64 + w*8][0]);
    };
    auto rdA = [&](int slot, int row, int g) -> bf16x8 {
        return *(const bf16x8*)&LA[slot][row][(g ^ (row & 7)) << 3];
    };
    auto rdB = [&](int slot, int row, int g) -> bf16x8 {
        return *(const bf16x8*)&LB[slot][row][(g ^ (row & 7)) << 3];
    };

    f32x4  acc[8][4] = {};
    bf16x8 bB[4][2];

    stageA(0, 0, 0); stageA(0, 1, 0);
    stageB(0, 0, 0); stageB(0, 1, 0);
    stageB(1, 0, 1); stageB(1, 1, 1);
    VMCNT4;
    SBAR();

#define PHASE(SLOT, Q, STG, VMC) \
  { \
    if (Q == 0) { \
      _Pragma("unroll") for (int j = 0; j < 4; ++j) \
      _Pragma("unroll") for (int ks = 0; ks < 2; ++ks) \
        bB[j][ks] = rdB(SLOT, wcn*64 + j*16 + fr, ks*4 + fq); \
    } \
    bf16x8 bA[2][2]; \
    _Pragma("unroll") for (int fi = 0; fi < 2; ++fi) \
    _Pragma("unroll") for (int ks = 0; ks < 2; ++ks) \
      bA[fi][ks] = rdA(SLOT, wrm*128 + (Q*2+fi)*16 + fr, ks*4 + fq); \
    STG; \
    VMC; \
    SBAR(); SCHED0(); \
    if (!wskip) { \
      __builtin_amdgcn_s_setprio(1); \
      _Pragma("unroll") for (int fi = 0; fi < 2; ++fi) \
      _Pragma("unroll") for (int j = 0; j < 4; ++j) \
      _Pragma("unroll") for (int ks = 0; ks < 2; ++ks) \
        acc[Q*2+fi][j] = __builtin_amdgcn_mfma_f32_16x16x32_bf16( \
            bA[fi][ks], bB[j][ks], acc[Q*2+fi][j], 0, 0, 0); \
      __builtin_amdgcn_s_setprio(0); \
    } \
    SCHED0(); SBAR(); \
  }

    for (int i = 0; i < NI; ++i) {
        const bool nl = (i < NI - 1);
        const int k1 = 2*i + 1, k2 = 2*i + 2, k3 = 2*i + 3;
        PHASE(0, 0, stageA(k1, 0, 1), );
        PHASE(0, 1, stageA(k1, 1, 1), );
        PHASE(0, 2, if (nl) stageB(k2, 0, 0), );
        PHASE(0, 3, if (nl) stageB(k2, 1, 0), if (nl) { VMCNT4; } else { VMCNT0; });
        PHASE(1, 0, if (nl) stageA(k2, 0, 0), );
        PHASE(1, 1, if (nl) stageA(k2, 1, 0), );
        PHASE(1, 2, if (nl) stageB(k3, 0, 1), );
        PHASE(1, 3, if (nl) stageB(k3, 1, 1), if (nl) { VMCNT4; });
    }
#undef PHASE

    const ll coff = (ll)bz * batchC;
    float s4[4] = {0.f, 0.f, 0.f, 0.f};
    #pragma unroll
    for (int fi = 0; fi < 8; ++fi)
    #pragma unroll
    for (int j = 0; j < 4; ++j)
    #pragma unroll
    for (int r4 = 0; r4 < 4; ++r4) {
        const int row = row0 + wrm*128 + fi*16 + fq*4 + r4;
        const int col = col0 + wcn*64 + j*16 + fr;
        float v = acc[fi][j][r4];
        if (OP == 0) {
            v += bias[col];
            ((__bf16*)Cp)[coff + (ll)row * ldc + col] = (__bf16)v;
        } else if (OP == 1) {
            float e = (msk && col > row) ? 0.f : __expf(v * 0.03125f);
            __bf16 eb = (__bf16)e;
            ((__bf16*)Cp)[coff + (ll)row * ldc + col] = eb;
            s4[j] += (float)eb;
        } else {
            ((float*)Cp)[coff + (ll)row * ldc + col] = v;
        }
    }
    if (OP == 1 && part != nullptr) {
        float* red = (float*)&LA[0][0][0];
        __syncthreads();
        #pragma unroll
        for (int j = 0; j < 4; ++j)
            red[(wrm*4 + fq)*256 + wcn*64 + j*16 + fr] = s4[j];
        __syncthreads();
        if (t < 256) {
            float tot = 0.f;
            #pragma unroll
            for (int r = 0; r < 8; ++r) tot += red[r*256 + t];
            part[((ll)bx * 8 + bz) * 2048 + col0 + t] = tot;
        }
    }
}

// ---------------------------------------------------------------------------
// PV (round-20 config — chunked XCD swizzle, interleaved attn slices,
// masked slice fast path; best measured, frozen).
// ---------------------------------------------------------------------------
__global__ __launch_bounds__(512) void pv64(
    const __bf16* __restrict__ E, const __bf16* __restrict__ VT,
    const float* __restrict__ inv, float* __restrict__ out,
    float* __restrict__ attn, const int* __restrict__ maskp)
{
    __shared__ __bf16 LA[2][64][64];     // 16 KB
    __shared__ __bf16 LB[2][256][64];    // 64 KB

    // chunked XCD swizzle over flat [0,1024)
    const int f   = (int)blockIdx.x + 128 * (int)blockIdx.z;
    const int swz = (f & 7) * 128 + (f >> 3);
    const int n   = swz & 127;
    const int bz  = swz >> 7;
    const int by  = n & 3;
    const int bxr = 31 - (n >> 2);       // longest first within chunk
    const int t = threadIdx.x, w = t >> 6, lane = t & 63;
    const int wrm = w >> 2, wcn = w & 3;
    const int fr = lane & 15, fq = lane >> 4;
    const int row0 = bxr * 64, col0 = by * 256;
    const int msk = maskp[0];

    int NT = msk ? ((bxr + 2) & ~1) : 32;
    const int NI = NT / 2;

    const __bf16* Ab = E  + (ll)bz * 2048 * 2048;
    const __bf16* Bb = VT + (ll)bz * 1024 * 2048;

    // attn-slice setup: cols by*512..+512, rows row0..+64 (8 slices x 8 rows)
    const int c0 = by * 512;
    const int ct = (t & 63) * 8;
    const int r00 = t >> 6;              // 0..7
    f32x4 ivlo = *(const f32x4*)&inv[bz*2048 + c0 + ct];
    f32x4 ivhi = *(const f32x4*)&inv[bz*2048 + c0 + ct + 4];

    auto slice = [&](int s) {
        const int row = row0 + s*8 + r00;
        float* ao = attn + (ll)bz*2048*2048 + (ll)row*2048 + c0 + ct;
        if (msk && c0 > row0 + s*8 + 7) {      // whole slice above diagonal
            f32x4 z = {};
            ((f32x4*)ao)[0] = z;
            ((f32x4*)ao)[1] = z;
            return;
        }
        bf16x8 ev = *(const bf16x8*)&Ab[(ll)row*2048 + c0 + ct];
        f32x4 lo, hi;
        #pragma unroll
        for (int e = 0; e < 4; ++e) {
            lo[e] = (float)ev[e]     * ivlo[e];
            hi[e] = (float)ev[e + 4] * ivhi[e];
        }
        ((f32x4*)ao)[0] = lo;
        ((f32x4*)ao)[1] = hi;
    };

    const int srow = lane >> 3;
    const int cg   = (lane & 7) ^ srow;

    auto stageA = [&](int kt, int slot) {
        GLD(Ab + (ll)(row0 + w*8 + srow) * 2048 + kt*64 + cg*8,
            &LA[slot][w*8][0]);
    };
    auto stageB = [&](int kt, int slot) {
        #pragma unroll
        for (int h = 0; h < 2; ++h)
        #pragma unroll
        for (int is = 0; is < 2; ++is)
            GLD(Bb + (ll)(col0 + h*128 + is*64 + w*8 + srow) * 2048 + kt*64 + cg*8,
                &LB[slot][h*128 + is*64 + w*8][0]);
    };
    auto rdA = [&](int slot, int row, int g) -> bf16x8 {
        return *(const bf16x8*)&LA[slot][row][(g ^ (row & 7)) << 3];
    };
    auto rdB = [&](int slot, int row, int g) -> bf16x8 {
        return *(const bf16x8*)&LB[slot][row][(g ^ (row & 7)) << 3];
    };

    f32x4  acc[2][4] = {};
    bf16x8 bB[4][2];

    // prologue
    stageA(0, 0); stageB(0, 0);
    stageB(1, 1);
    VMCNT4;
    SBAR();

#define PHASEP(SLOT, Q, STG, VMC) \
  { \
    if (Q == 0) { \
      _Pragma("unroll") for (int j = 0; j < 4; ++j) \
      _Pragma("unroll") for (int ks = 0; ks < 2; ++ks) \
        bB[j][ks] = rdB(SLOT, wcn*64 + j*16 + fr, ks*4 + fq); \
    } \
    bf16x8 bA[2]; \
    _Pragma("unroll") for (int ks = 0; ks < 2; ++ks) \
      bA[ks] = rdA(SLOT, wrm*32 + Q*16 + fr, ks*4 + fq); \
    STG; \
    VMC; \
    SBAR(); SCHED0(); \
    __builtin_amdgcn_s_setprio(1); \
    _Pragma("unroll") for (int j = 0; j < 4; ++j) \
    _Pragma("unroll") for (int ks = 0; ks < 2; ++ks) \
      acc[Q][j] = __builtin_amdgcn_mfma_f32_16x16x32_bf16( \
          bA[ks], bB[j][ks], acc[Q][j], 0, 0, 0); \
    __builtin_amdgcn_s_setprio(0); \
    SCHED0(); SBAR(); \
  }

    for (int i = 0; i < NI; ++i) {
        const bool nl = (i < NI - 1);
        const int kb = 2*i + 1, ka2 = 2*i + 2, kb2 = 2*i + 3;
        PHASEP(0, 0, stageA(kb, 1), );
        PHASEP(0, 1, if (nl) stageB(ka2, 0),
                     if (nl) { VMCNT4; } else { VMCNT0; });
        PHASEP(1, 0, if (nl) stageA(ka2, 0), );
        PHASEP(1, 1, if (nl) stageB(kb2, 1),
                     if (nl) { VMCNT4; });
        if (i < 8) slice(i);             // overlapped attn write
    }
#undef PHASEP

    // remaining attn slices (short-K blocks)
    for (int s = (NI < 8 ? NI : 8); s < 8; ++s) slice(s);

    // out stores
    #pragma unroll
    for (int qf = 0; qf < 2; ++qf)
    #pragma unroll
    for (int j = 0; j < 4; ++j)
    #pragma unroll
    for (int r4 = 0; r4 < 4; ++r4) {
        const int row = row0 + wrm*32 + qf*16 + fq*4 + r4;
        const int col = col0 + wcn*64 + j*16 + fr;
        out[(ll)bz*2048*1024 + (ll)row*1024 + col] = acc[qf][j][r4];
    }
}

// ---------------------------------------------------------------------------
// All input conversions in ONE launch.
// ---------------------------------------------------------------------------
__global__ __launch_bounds__(256) void cvtall_k(
    const float* __restrict__ X,  const float* __restrict__ Wq,
    const float* __restrict__ Wk, const float* __restrict__ Wv,
    const float* __restrict__ bq, const float* __restrict__ bk,
    const float* __restrict__ bv,
    __bf16* __restrict__ Xb, __bf16* __restrict__ Wb, float* __restrict__ bb)
{
    const int b = blockIdx.x;
    if (b < 9728) {
        const float* src;
        __bf16* dst;
        ll i;
        if (b < 8192)      { src = X;  dst = Xb;             i = (ll)b * 256 + threadIdx.x; }
        else if (b < 8704) { src = Wq; dst = Wb;             i = (ll)(b - 8192) * 256 + threadIdx.x; }
        else if (b < 9216) { src = Wk; dst = Wb + 1024*1024; i = (ll)(b - 8704) * 256 + threadIdx.x; }
        else               { src = Wv; dst = Wb + 2048*1024; i = (ll)(b - 9216) * 256 + threadIdx.x; }
        const f32x4* p = (const f32x4*)(src + i * 8);
        f32x4 a = p[0], c = p[1];
        bf16x8 h;
        #pragma unroll
        for (int j = 0; j < 4; ++j) { h[j] = (__bf16)a[j]; h[j + 4] = (__bf16)c[j]; }
        *(bf16x8*)(dst + i * 8) = h;
    } else {
        const int i = (b - 9728) * 256 + threadIdx.x;   // 0..3071
        bb[i] = (i < 1024) ? bq[i] : (i < 2048) ? bk[i - 1024] : bv[i - 2048];
    }
}

// ---------------------------------------------------------------------------
// vtpf: V' transpose with INLINE colsum reduction; publishes inv[].
// ---------------------------------------------------------------------------
__global__ __launch_bounds__(256) void vtpf_k(const __bf16* __restrict__ qkv,
                                              const float* __restrict__ part,
                                              float* __restrict__ inv,
                                              __bf16* __restrict__ vt)
{
    __shared__ __bf16 tile[64][72];
    const int t  = threadIdx.x;
    const int m0 = blockIdx.x * 64;
    const int k0 = blockIdx.y * 64;
    const int b  = blockIdx.z;

    const __bf16* V = qkv + (ll)b * 2048 * 3072 + 2048;
    #pragma unroll
    for (int h = 0; h < 2; ++h) {
        int r = (t >> 3) + h * 32;
        int c = (t & 7) * 8;
        int m = m0 + r;
        float s = 0.f;
        #pragma unroll
        for (int lc = 0; lc < 8; ++lc) s += part[((ll)lc * 8 + b) * 2048 + m];
        const float iv = 1.0f / s;
        if (k0 == 0 && (t & 7) == 0) inv[b * 2048 + m] = iv;
        bf16x8 v = *(const bf16x8*)&V[(ll)m * 3072 + k0 + c];
        bf16x8 o;
        #pragma unroll
        for (int j = 0; j < 8; ++j) o[j] = (__bf16)((float)v[j] * iv);
        *(bf16x8*)&tile[r][c] = o;
    }
    __syncthreads();
    __bf16* O = vt + (ll)b * 1024 * 2048;
    #pragma unroll
    for (int h = 0; h < 2; ++h) {
        int k = (t >> 3) + h * 32;
        int m = (t & 7) * 8;
        bf16x8 o;
        #pragma unroll
        for (int j = 0; j < 8; ++j) o[j] = tile[m + j][k];
        *(bf16x8*)&O[(ll)(k0 + k) * 2048 + m0 + m] = o;
    }
}

// plain V transpose (fallback path)
__global__ __launch_bounds__(256) void vt_k(const unsigned short* __restrict__ qkv,
                                            unsigned short* __restrict__ vt)
{
    __shared__ unsigned short tile[64][72];
    const int t  = threadIdx.x;
    const int m0 = blockIdx.x * 64;
    const int k0 = blockIdx.y * 64;
    const int b  = blockIdx.z;

    const unsigned short* V = qkv + (ll)b * 2048 * 3072 + 2048;
    #pragma unroll
    for (int h = 0; h < 2; ++h) {
        int r = (t >> 3) + h * 32;
        int c = (t & 7) * 8;
        us8 v = *(const us8*)&V[(ll)(m0 + r) * 3072 + k0 + c];
        *(us8*)&tile[r][c] = v;
    }
    __syncthreads();
    unsigned short* O = vt + (ll)b * 1024 * 2048;
    #pragma unroll
    for (int h = 0; h < 2; ++h) {
        int k = (t >> 3) + h * 32;
        int m = (t & 7) * 8;
        us8 o;
        #pragma unroll
        for (int j = 0; j < 8; ++j) o[j] = tile[m + j][k];
        *(us8*)&O[(ll)(k0 + k) * 2048 + m0 + m] = o;
    }
}

// fallback-path aux
__global__ __launch_bounds__(256) void colsum_k(const __bf16* __restrict__ E,
                                                float* __restrict__ part)
{
    const int lc = blockIdx.x, mc = blockIdx.y, b = blockIdx.z;
    const int m  = mc * 256 + threadIdx.x;
    const __bf16* p = E + (ll)b * 2048 * 2048 + (ll)(lc * 256) * 2048 + m;
    float s = 0.f;
    #pragma unroll 4
    for (int l = 0; l < 256; ++l) s += (float)p[(ll)l * 2048];
    part[((ll)lc * 8 + b) * 2048 + m] = s;
}

__global__ __launch_bounds__(256) void norm_k(const __bf16* __restrict__ E,
                                              const float* __restrict__ part,
                                              float* __restrict__ attn,
                                              __bf16* __restrict__ attn_bf)
{
    const int lc = blockIdx.x, mc = blockIdx.y, b = blockIdx.z;
    const int m  = mc * 256 + threadIdx.x;
    float s = 0.f;
    #pragma unroll
    for (int j = 0; j < 8; ++j) s += part[((ll)j * 8 + b) * 2048 + m];
    const float iv = 1.0f / s;
    const __bf16* p = E + (ll)b * 2048 * 2048 + (ll)(lc * 256) * 2048 + m;
    float*  qo = attn    + (ll)b * 2048 * 2048 + (ll)(lc * 256) * 2048 + m;
    __bf16* ro = attn_bf + (ll)b * 2048 * 2048 + (ll)(lc * 256) * 2048 + m;
    #pragma unroll 4
    for (int l = 0; l < 256; ++l) {
        float a = (float)p[(ll)l * 2048] * iv;
        qo[(ll)l * 2048] = a;
        ro[(ll)l * 2048] = (__bf16)a;
    }
}

// ---------------------------------------------------------------------------
extern "C" void kernel_launch(void* const* d_in, const int* in_sizes, int n_in,
                              void* d_out, int out_size, void* d_ws, size_t ws_size,
                              hipStream_t stream)
{
    const float* X   = (const float*)d_in[0];
    const float* Wq  = (const float*)d_in[1];
    const float* bq  = (const float*)d_in[2];
    const float* Wk  = (const float*)d_in[3];
    const float* bk  = (const float*)d_in[4];
    const float* Wv  = (const float*)d_in[5];
    const float* bv  = (const float*)d_in[6];
    const int*   msk = (const int*)d_in[7];

    float* out  = (float*)d_out;                  // (8,2048,1024) fp32
    float* attn = out + (ll)8 * 2048 * 1024;      // (8,2048,2048) fp32

    __bf16* Xb = (__bf16*)attn;                   // staging in attn region
    __bf16* Wb = Xb + (ll)16384 * 1024;
    float*  bb = (float*)(Wb + (ll)3072 * 1024);

    __bf16* qkv = (__bf16*)d_ws;                  // 96 MiB
    __bf16* vt  = qkv + (ll)16384 * 3072;         // 32 MiB

    // 0) all bf16 conversions in one launch
    cvtall_k<<<dim3(9740), 256, 0, stream>>>(X, Wq, Wk, Wv, bq, bk, bv,
                                             Xb, Wb, bb);

    // 1) QKV projection
    gemm8<0><<<dim3(64, 12, 1), 512, 0, stream>>>(
        Xb, Wb, qkv, bb, msk, nullptr,
        1024, 1024, 1024, 3072, 0LL, 0LL, 0LL);

    const size_t need_fused =
        (size_t)(16384ll*3072 + 8ll*1024*2048 + 8ll*2048*2048) * 2
        + (size_t)(8*8*2048 + 8*2048) * 4;

    if (ws_size >= need_fused) {
        // fused path: E in ws, inv folded into V^T, attn fused into PV
        __bf16* E   = vt + (ll)8 * 1024 * 2048;
        float*  prt = (float*)(E + (ll)8 * 2048 * 2048);
        float*  inv = prt + 8 * 8 * 2048;

        // 2) E = exp(QK^T/32, masked) -> ws; fused col sums; XCD-chunked
        gemm8<1><<<dim3(8, 8, 8), 512, 0, stream>>>(
            qkv, qkv + 1024, E, nullptr, msk, prt,
            1024, 3072, 3072, 2048,
            (ll)2048 * 3072, (ll)2048 * 3072, (ll)2048 * 2048);

        // 3) vt = (V * inv)^T with inline colsum reduce; publishes inv[]
        vtpf_k<<<dim3(32, 16, 8), 256, 0, stream>>>(qkv, prt, inv, vt);

        // 4) out = E @ vt^T + attn slices; chunked XCD swizzle for E reuse
        pv64<<<dim3(128, 1, 8), 512, 0, stream>>>(E, vt, inv, out, attn, msk);
    } else {
        // fallback: round-4 proven pipeline
        __bf16* E   = (__bf16*)d_out;
        float*  prt = (float*)(vt + (ll)8 * 1024 * 2048);
        __bf16* attn_bf = qkv;

        vt_k<<<dim3(32, 16, 8), 256, 0, stream>>>((const unsigned short*)qkv,
                                                  (unsigned short*)vt);

        gemm8<1><<<dim3(8, 8, 8), 512, 0, stream>>>(
            qkv, qkv + 1024, E, nullptr, msk, nullptr,
            1024, 3072, 3072, 2048,
            (ll)2048 * 3072, (ll)2048 * 3072, (ll)2048 * 2048);

        colsum_k<<<dim3(8, 8, 8), 256, 0, stream>>>(E, prt);
        norm_k<<<dim3(8, 8, 8), 256, 0, stream>>>(E, prt, attn, attn_bf);

        gemm8<2><<<dim3(8, 4, 8), 512, 0, stream>>>(
            attn_bf, vt, out, nullptr, msk, nullptr,
            2048, 2048, 2048, 1024,
            (ll)2048 * 2048, (ll)1024 * 2048, (ll)2048 * 1024);
    }
}